// Round 1
// baseline (2081.589 us; speedup 1.0000x reference)
//
#include <hip/hip_runtime.h>
#include <math.h>

#define NODES 20000
#define EDGES 320000
#define DIN 128
#define HID 256
#define NGRAPH 32
#define NREL 6

// ---------------- CSR build ----------------
__global__ void k_hist(const int* __restrict__ edges, int* __restrict__ cnt) {
  int idx = blockIdx.x * blockDim.x + threadIdx.x;
  if (idx >= NREL * EDGES) return;
  int r = idx / EDGES;
  int e = idx - r * EDGES;
  int dst = edges[(r * 2 + 1) * EDGES + e];
  atomicAdd(&cnt[r * NODES + dst], 1);
}

__global__ __launch_bounds__(1024) void k_scan(const int* __restrict__ cnt,
                                               int* __restrict__ rowoff) {
  int r = blockIdx.x;
  __shared__ int sh[1024];
  int running = 0;
  for (int base = 0; base < NODES; base += 1024) {
    int i = base + threadIdx.x;
    int v = (i < NODES) ? cnt[r * NODES + i] : 0;
    sh[threadIdx.x] = v;
    __syncthreads();
    for (int s = 1; s < 1024; s <<= 1) {
      int t = (threadIdx.x >= s) ? sh[threadIdx.x - s] : 0;
      __syncthreads();
      sh[threadIdx.x] += t;
      __syncthreads();
    }
    if (i < NODES) rowoff[r * (NODES + 1) + i] = running + sh[threadIdx.x] - v;
    int tot = sh[1023];
    __syncthreads();
    running += tot;
  }
  if (threadIdx.x == 0) rowoff[r * (NODES + 1) + NODES] = running;
}

__global__ void k_scatter(const int* __restrict__ edges, const int* __restrict__ rowoff,
                          int* __restrict__ cur, int* __restrict__ csr) {
  int idx = blockIdx.x * blockDim.x + threadIdx.x;
  if (idx >= NREL * EDGES) return;
  int r = idx / EDGES;
  int e = idx - r * EDGES;
  int src = edges[(r * 2 + 0) * EDGES + e];
  int dst = edges[(r * 2 + 1) * EDGES + e];
  int p = atomicAdd(&cur[r * NODES + dst], 1);
  csr[r * EDGES + rowoff[r * (NODES + 1) + dst] + p] = src;
}

// ---------------- Aggregation (segment mean via CSR) ----------------
__global__ __launch_bounds__(256) void k_agg(const float* __restrict__ xs_src,
                                             const int* __restrict__ rowoff,
                                             const int* __restrict__ csr,
                                             float* __restrict__ agg, int r) {
  int row = blockIdx.x;
  int c = threadIdx.x;
  const int* ro = rowoff + r * (NODES + 1);
  int o0 = ro[row], o1 = ro[row + 1];
  const int* lst = csr + r * EDGES;
  float s = 0.f;
  for (int j = o0; j < o1; ++j) {
    int sidx = lst[j];
    s += xs_src[(size_t)sidx * HID + c];
  }
  float inv = (o1 > o0) ? 1.f / (float)(o1 - o0) : 0.f;
  agg[(size_t)row * HID + c] = s * inv;
}

// ---------------- fp32 GEMM: C[M x 256] = sum_seg A_seg[M x KSEG] @ B_seg[KSEG x 256] + bias ----
template <int KSEG, int NSEG>
__global__ __launch_bounds__(256) void k_gemm(
    const float* __restrict__ A0, const float* __restrict__ A1,
    const float* __restrict__ A2, const float* __restrict__ A3,
    const float* __restrict__ B0, const float* __restrict__ B1,
    const float* __restrict__ B2, const float* __restrict__ B3,
    const float* __restrict__ bias, float* __restrict__ C) {
  __shared__ float As[16][68];
  __shared__ float Bs[16][68];
  const int bm = blockIdx.x * 64;
  const int bn = blockIdx.y * 64;
  const int tid = threadIdx.x;
  const int tx = tid & 15;
  const int ty = tid >> 4;
  const int lrow = tid >> 2;        // 0..63 (A tile row)
  const int lk4 = (tid & 3) * 4;    // 0,4,8,12 (A tile k)
  const int brow = tid >> 4;        // 0..15 (B tile k)
  const int bcol = (tid & 15) * 4;  // 0..60 (B tile col)
  float acc[4][4] = {};
  const float* APs[4] = {A0, A1, A2, A3};
  const float* BPs[4] = {B0, B1, B2, B3};
#pragma unroll
  for (int seg = 0; seg < NSEG; ++seg) {
    const float* __restrict__ A = APs[seg];
    const float* __restrict__ B = BPs[seg];
    for (int k0 = 0; k0 < KSEG; k0 += 16) {
      float4 av = make_float4(0.f, 0.f, 0.f, 0.f);
      int ar = bm + lrow;
      if (ar < NODES) av = *(const float4*)(A + (size_t)ar * KSEG + k0 + lk4);
      As[lk4 + 0][lrow] = av.x;
      As[lk4 + 1][lrow] = av.y;
      As[lk4 + 2][lrow] = av.z;
      As[lk4 + 3][lrow] = av.w;
      float4 bv = *(const float4*)(B + (size_t)(k0 + brow) * HID + bn + bcol);
      *(float4*)&Bs[brow][bcol] = bv;
      __syncthreads();
#pragma unroll
      for (int kk = 0; kk < 16; ++kk) {
        float4 a = *(const float4*)&As[kk][ty * 4];
        float4 b = *(const float4*)&Bs[kk][tx * 4];
        float ar4[4] = {a.x, a.y, a.z, a.w};
        float br4[4] = {b.x, b.y, b.z, b.w};
#pragma unroll
        for (int i = 0; i < 4; ++i)
#pragma unroll
          for (int j = 0; j < 4; ++j) acc[i][j] = fmaf(ar4[i], br4[j], acc[i][j]);
      }
      __syncthreads();
    }
  }
  int crow0 = bm + ty * 4;
  int ccol = bn + tx * 4;
  float b0 = bias[ccol + 0], b1 = bias[ccol + 1], b2 = bias[ccol + 2], b3 = bias[ccol + 3];
#pragma unroll
  for (int i = 0; i < 4; ++i) {
    int rrow = crow0 + i;
    if (rrow < NODES) {
      float4 o;
      o.x = acc[i][0] + b0;
      o.y = acc[i][1] + b1;
      o.z = acc[i][2] + b2;
      o.w = acc[i][3] + b3;
      *(float4*)(C + (size_t)rrow * HID + ccol) = o;
    }
  }
}

// ---------------- per-layer weight/bias sums; zero BN stats ----------------
__global__ void k_wsum(const float* __restrict__ W_r, const float* __restrict__ b_l,
                       float* __restrict__ wrsum, float* __restrict__ bsum,
                       float* __restrict__ stats, int layer) {
  int idx = blockIdx.x * blockDim.x + threadIdx.x;
  const size_t WB = (size_t)layer * NREL * HID * HID;
  const int HH = HID * HID;
  if (idx < HH) {
    wrsum[idx] = W_r[WB + 0 * HH + idx] + W_r[WB + 1 * HH + idx] + W_r[WB + 3 * HH + idx];
    wrsum[HH + idx] = W_r[WB + 2 * HH + idx] + W_r[WB + 4 * HH + idx] + W_r[WB + 5 * HH + idx];
  }
  if (idx < HID) {
    const int bb = layer * NREL * HID;
    bsum[idx] = b_l[bb + 0 * HID + idx] + b_l[bb + 1 * HID + idx] + b_l[bb + 3 * HID + idx];
    bsum[HID + idx] = b_l[bb + 2 * HID + idx] + b_l[bb + 4 * HID + idx] + b_l[bb + 5 * HID + idx];
  }
  if (idx < 2 * 2 * HID) stats[idx] = 0.f;
}

// ---------------- BatchNorm ----------------
__global__ __launch_bounds__(256) void k_bnstats(const float* __restrict__ acc,
                                                 float* __restrict__ stats) {
  int c = threadIdx.x;
  int rows_per = (NODES + gridDim.x - 1) / gridDim.x;
  int r0 = blockIdx.x * rows_per;
  int r1 = min(NODES, r0 + rows_per);
  if (r0 >= NODES) return;
  float s = 0.f, s2 = 0.f;
  for (int r = r0; r < r1; ++r) {
    float v = acc[(size_t)r * HID + c];
    s += v;
    s2 = fmaf(v, v, s2);
  }
  atomicAdd(&stats[c], s);
  atomicAdd(&stats[HID + c], s2);
}

__global__ __launch_bounds__(256) void k_bnapply(const float* __restrict__ accin,
                                                 const float* __restrict__ stats,
                                                 const float* __restrict__ gamma,
                                                 const float* __restrict__ beta,
                                                 const float* __restrict__ prev,
                                                 float* __restrict__ out, int addprev) {
  int idx = blockIdx.x * 256 + threadIdx.x;
  if (idx >= NODES * HID) return;
  int c = idx & (HID - 1);
  const float inv3 = (1.f / 3.f);
  float m = stats[c] * (inv3 / NODES);
  float ex2 = stats[HID + c] * (inv3 * inv3 / NODES);
  float var = ex2 - m * m;
  float y = accin[idx] * inv3;
  float v = (y - m) * rsqrtf(var + 1e-5f) * gamma[c] + beta[c];
  v = fmaxf(v, 0.f);
  if (addprev) v += prev[idx];
  out[idx] = v;
}

// ---------------- pooling ----------------
__global__ __launch_bounds__(256) void k_pool(const float* __restrict__ xs,
                                              const int* __restrict__ batch,
                                              float* __restrict__ pooled,
                                              float* __restrict__ gcnt) {
  int c = threadIdx.x;
  int rows_per = (NODES + gridDim.x - 1) / gridDim.x;
  int r0 = blockIdx.x * rows_per;
  int r1 = min(NODES, r0 + rows_per);
  if (r0 >= NODES) return;
  float s = 0.f;
  int curg = batch[r0];
  for (int r = r0; r < r1; ++r) {
    int g = batch[r];
    if (g != curg) {
      atomicAdd(&pooled[curg * HID + c], s);
      s = 0.f;
      curg = g;
    }
    s += xs[(size_t)r * HID + c];
  }
  atomicAdd(&pooled[curg * HID + c], s);
  if (c == 0) {
    int cnt = 0;
    int cg = batch[r0];
    for (int r = r0; r < r1; ++r) {
      int g = batch[r];
      if (g != cg) {
        atomicAdd(&gcnt[cg], (float)cnt);
        cnt = 0;
        cg = g;
      }
      cnt++;
    }
    atomicAdd(&gcnt[cg], (float)cnt);
  }
}

__global__ __launch_bounds__(256) void k_final(const float* __restrict__ pooled,
                                               const float* __restrict__ gcnt,
                                               const float* __restrict__ Wout,
                                               const float* __restrict__ bout,
                                               float* __restrict__ out) {
  int g = blockIdx.x;
  int h = threadIdx.x;
  float cv = fmaxf(gcnt[g], 1.f);
  float cp = fmaxf(gcnt[NGRAPH + g], 1.f);
  float v = pooled[g * HID + h] / cv * Wout[h] +
            pooled[NGRAPH * HID + g * HID + h] / cp * Wout[HID + h];
#pragma unroll
  for (int s = 32; s > 0; s >>= 1) v += __shfl_down(v, s, 64);
  __shared__ float sh[4];
  if ((h & 63) == 0) sh[h >> 6] = v;
  __syncthreads();
  if (h == 0) {
    float t = sh[0] + sh[1] + sh[2] + sh[3] + bout[0];
    out[g] = 1.f / (1.f + expf(-t));
  }
}

// ---------------- host ----------------
extern "C" void kernel_launch(void* const* d_in, const int* in_sizes, int n_in,
                              void* d_out, int out_size, void* d_ws, size_t ws_size,
                              hipStream_t stream) {
  const float* x_vuln = (const float*)d_in[0];
  const float* x_patch = (const float*)d_in[1];
  const float* W_emb = (const float*)d_in[2];
  const float* b_emb = (const float*)d_in[3];
  const float* W_l = (const float*)d_in[4];
  const float* b_l = (const float*)d_in[5];
  const float* W_r = (const float*)d_in[6];
  const float* gamma = (const float*)d_in[7];
  const float* beta = (const float*)d_in[8];
  const float* W_out = (const float*)d_in[9];
  const float* b_out = (const float*)d_in[10];
  const int* edge_index = (const int*)d_in[11];
  const int* batch_vuln = (const int*)d_in[12];
  const int* batch_patch = (const int*)d_in[13];

  char* ws = (char*)d_ws;
  size_t off = 0;
  auto alloc = [&](size_t bytes) -> void* {
    void* p = ws + off;
    off = (off + bytes + 255) & ~(size_t)255;
    return p;
  };
  int* csr = (int*)alloc((size_t)NREL * EDGES * 4);
  int* rowoff = (int*)alloc((size_t)NREL * (NODES + 1) * 4);
  int* cnt = (int*)alloc((size_t)NREL * NODES * 4);
  int* cur = (int*)alloc((size_t)NREL * NODES * 4);
  float* xsbuf[2][2];
  for (int b = 0; b < 2; ++b)
    for (int t = 0; t < 2; ++t) xsbuf[b][t] = (float*)alloc((size_t)NODES * HID * 4);
  float* aggb[3];
  for (int j = 0; j < 3; ++j) aggb[j] = (float*)alloc((size_t)NODES * HID * 4);
  float* wrsum = (float*)alloc((size_t)2 * HID * HID * 4);
  float* bsum = (float*)alloc((size_t)2 * HID * 4);
  float* stats = (float*)alloc((size_t)2 * 2 * HID * 4);  // [type][{sum,sumsq}][H]
  float* pooled = (float*)alloc((size_t)2 * NGRAPH * HID * 4);
  float* gcnt = (float*)alloc((size_t)2 * NGRAPH * 4);

  hipMemsetAsync(cnt, 0, (size_t)NREL * NODES * 4, stream);
  hipMemsetAsync(cur, 0, (size_t)NREL * NODES * 4, stream);
  hipMemsetAsync(pooled, 0, (size_t)2 * NGRAPH * HID * 4, stream);
  hipMemsetAsync(gcnt, 0, (size_t)2 * NGRAPH * 4, stream);

  // CSR build
  int tot_e = NREL * EDGES;
  k_hist<<<(tot_e + 255) / 256, 256, 0, stream>>>(edge_index, cnt);
  k_scan<<<NREL, 1024, 0, stream>>>(cnt, rowoff);
  k_scatter<<<(tot_e + 255) / 256, 256, 0, stream>>>(edge_index, rowoff, cur, csr);

  // input projection: xsbuf[0][t] = x_t @ W_emb[t] + b_emb[t]
  dim3 ggrid((NODES + 63) / 64, HID / 64);
  k_gemm<DIN, 1><<<ggrid, 256, 0, stream>>>(x_vuln, x_vuln, x_vuln, x_vuln,
                                            W_emb, W_emb, W_emb, W_emb,
                                            b_emb, xsbuf[0][0]);
  k_gemm<DIN, 1><<<ggrid, 256, 0, stream>>>(x_patch, x_patch, x_patch, x_patch,
                                            W_emb + DIN * HID, W_emb, W_emb, W_emb,
                                            b_emb + HID, xsbuf[0][1]);

  const int HH = HID * HID;
  // dt=0 rels {0,1,3} src {0,0,1};  dt=1 rels {2,4,5} src {0,1,1}
  const int rels[2][3] = {{0, 1, 3}, {2, 4, 5}};
  const int srct[2][3] = {{0, 0, 1}, {0, 1, 1}};

  for (int layer = 0; layer < 2; ++layer) {
    float** xin = xsbuf[layer & 1];
    float** xout = xsbuf[(layer + 1) & 1];
    k_wsum<<<256, 256, 0, stream>>>(W_r, b_l, wrsum, bsum, stats, layer);
    for (int dt = 0; dt < 2; ++dt) {
      for (int j = 0; j < 3; ++j)
        k_agg<<<NODES, 256, 0, stream>>>(xin[srct[dt][j]], rowoff, csr, aggb[j],
                                         rels[dt][j]);
      k_gemm<HID, 4><<<ggrid, 256, 0, stream>>>(
          aggb[0], aggb[1], aggb[2], xin[dt],
          W_l + (size_t)(layer * NREL + rels[dt][0]) * HH,
          W_l + (size_t)(layer * NREL + rels[dt][1]) * HH,
          W_l + (size_t)(layer * NREL + rels[dt][2]) * HH, wrsum + (size_t)dt * HH,
          bsum + dt * HID, xout[dt]);
      k_bnstats<<<128, 256, 0, stream>>>(xout[dt], stats + dt * 2 * HID);
      k_bnapply<<<(NODES * HID + 255) / 256, 256, 0, stream>>>(
          xout[dt], stats + dt * 2 * HID, gamma + (layer * 2 + dt) * HID,
          beta + (layer * 2 + dt) * HID, xin[dt], xout[dt], layer > 0 ? 1 : 0);
    }
  }

  // final xs lives in xsbuf[0] (layer1 wrote buf0)
  k_pool<<<64, 256, 0, stream>>>(xsbuf[0][0], batch_vuln, pooled, gcnt);
  k_pool<<<64, 256, 0, stream>>>(xsbuf[0][1], batch_patch, pooled + NGRAPH * HID,
                                 gcnt + NGRAPH);
  k_final<<<NGRAPH, 256, 0, stream>>>(pooled, gcnt, W_out, b_out, (float*)d_out);
}

// Round 2
// 896.815 us; speedup vs baseline: 2.3211x; 2.3211x over previous
//
#include <hip/hip_runtime.h>
#include <math.h>

#define NODES 20000
#define EDGES 320000
#define DIN 128
#define HID 256
#define NGRAPH 32
#define NREL 6

typedef __attribute__((ext_vector_type(8))) short bf16x8;
typedef __attribute__((ext_vector_type(8))) unsigned short u16x8;
typedef __attribute__((ext_vector_type(4))) float f32x4;

__device__ __forceinline__ float bf2f(unsigned short u) {
  return __uint_as_float(((unsigned)u) << 16);
}
__device__ __forceinline__ unsigned short f2bf(float f) {
  unsigned u = __float_as_uint(f);
  unsigned r = (u + 0x7fffu + ((u >> 16) & 1u)) >> 16;
  return (unsigned short)r;
}

#define GLDS(g, l)                                                            \
  __builtin_amdgcn_global_load_lds(                                           \
      (const __attribute__((address_space(1))) void*)(g),                     \
      (__attribute__((address_space(3))) void*)(l), 16, 0, 0)

// ---------------- CSR build ----------------
__global__ void k_hist(const int* __restrict__ edges, int* __restrict__ cnt) {
  int idx = blockIdx.x * blockDim.x + threadIdx.x;
  if (idx >= NREL * EDGES) return;
  int r = idx / EDGES;
  int e = idx - r * EDGES;
  int dst = edges[(r * 2 + 1) * EDGES + e];
  atomicAdd(&cnt[r * NODES + dst], 1);
}

__global__ __launch_bounds__(1024) void k_scan(const int* __restrict__ cnt,
                                               int* __restrict__ rowoff) {
  int r = blockIdx.x;
  __shared__ int sh[1024];
  int running = 0;
  for (int base = 0; base < NODES; base += 1024) {
    int i = base + threadIdx.x;
    int v = (i < NODES) ? cnt[r * NODES + i] : 0;
    sh[threadIdx.x] = v;
    __syncthreads();
    for (int s = 1; s < 1024; s <<= 1) {
      int t = (threadIdx.x >= s) ? sh[threadIdx.x - s] : 0;
      __syncthreads();
      sh[threadIdx.x] += t;
      __syncthreads();
    }
    if (i < NODES) rowoff[r * (NODES + 1) + i] = running + sh[threadIdx.x] - v;
    int tot = sh[1023];
    __syncthreads();
    running += tot;
  }
  if (threadIdx.x == 0) rowoff[r * (NODES + 1) + NODES] = running;
}

__global__ void k_scatter(const int* __restrict__ edges, const int* __restrict__ rowoff,
                          int* __restrict__ cur, int* __restrict__ csr) {
  int idx = blockIdx.x * blockDim.x + threadIdx.x;
  if (idx >= NREL * EDGES) return;
  int r = idx / EDGES;
  int e = idx - r * EDGES;
  int src = edges[(r * 2 + 0) * EDGES + e];
  int dst = edges[(r * 2 + 1) * EDGES + e];
  int p = atomicAdd(&cur[r * NODES + dst], 1);
  csr[r * EDGES + rowoff[r * (NODES + 1) + dst] + p] = src;
}

// ---------------- prep: x -> bf16 ----------------
__global__ void k_xcvt(const float* __restrict__ xv, const float* __restrict__ xp,
                       unsigned short* __restrict__ xbf) {
  int idx = blockIdx.x * 256 + threadIdx.x;
  const int ND = NODES * DIN;
  if (idx >= 2 * ND) return;
  float v = (idx < ND) ? xv[idx] : xp[idx - ND];
  xbf[idx] = f2bf(v);
}

// ---------------- prep: weight concat transpose -> bf16 ----------------
// Wt[ld=layer*2+dt][n(256)][k(1024)]; k = seg*256+kk
// seg<3: W_l[layer][rels[dt][seg]][kk][n];  seg3: sum_j W_r[layer][rels[dt][j]][kk][n]
__global__ void k_wtrans(const float* __restrict__ W_l, const float* __restrict__ W_r,
                         unsigned short* __restrict__ Wt) {
  const int rels[2][3] = {{0, 1, 3}, {2, 4, 5}};
  int kt = blockIdx.x, nt = blockIdx.y, ld = blockIdx.z;
  int layer = ld >> 1, dt = ld & 1;
  __shared__ float sh[16][17];
  int k0 = kt * 16, n0 = nt * 16;
  int seg = k0 >> 8, kk0 = k0 & 255;
  int tx = threadIdx.x, ty = threadIdx.y;
  float v;
  if (seg < 3) {
    v = W_l[(((size_t)layer * NREL + rels[dt][seg]) * HID + kk0 + ty) * HID + n0 + tx];
  } else {
    v = 0.f;
    for (int j = 0; j < 3; ++j)
      v += W_r[(((size_t)layer * NREL + rels[dt][j]) * HID + kk0 + ty) * HID + n0 + tx];
  }
  sh[ty][tx] = v;
  __syncthreads();
  Wt[((size_t)ld * HID + n0 + ty) * 1024 + k0 + tx] = f2bf(sh[tx][ty]);
}

__global__ void k_wembt(const float* __restrict__ W_emb, unsigned short* __restrict__ Wet) {
  int kt = blockIdx.x, nt = blockIdx.y, t = blockIdx.z;
  __shared__ float sh[16][17];
  int k0 = kt * 16, n0 = nt * 16;
  int tx = threadIdx.x, ty = threadIdx.y;
  sh[ty][tx] = W_emb[((size_t)t * DIN + k0 + ty) * HID + n0 + tx];
  __syncthreads();
  Wet[((size_t)t * HID + n0 + ty) * DIN + k0 + tx] = f2bf(sh[tx][ty]);
}

__global__ void k_bsum(const float* __restrict__ b_l, float* __restrict__ bsum,
                       float* __restrict__ stats, int layer) {
  const int rels[2][3] = {{0, 1, 3}, {2, 4, 5}};
  int idx = blockIdx.x * 256 + threadIdx.x;
  if (idx < 512) {
    int dt = idx >> 8, c = idx & 255;
    float s = 0.f;
    for (int j = 0; j < 3; ++j) s += b_l[(layer * NREL + rels[dt][j]) * HID + c];
    bsum[idx] = s;
  }
  if (idx < 1024) stats[idx] = 0.f;
}

// ---------------- fused aggregation: all 6 relations of a layer ----------------
// grid (5000, 3, 2): z=dt, y=seg. one wave per dst row.
__global__ __launch_bounds__(256) void k_agg(unsigned short* __restrict__ a0,
                                             unsigned short* __restrict__ a1,
                                             const int* __restrict__ rowoff,
                                             const int* __restrict__ csr) {
  const int rels[2][3] = {{0, 1, 3}, {2, 4, 5}};
  const int srct[2][3] = {{0, 0, 1}, {0, 1, 1}};
  int seg = blockIdx.y, dt = blockIdx.z;
  int r = rels[dt][seg], st = srct[dt][seg];
  const unsigned short* src = (st == 0 ? a0 : a1) + 768;  // xs slice, stride 1024
  unsigned short* dst = (dt == 0 ? a0 : a1) + seg * 256;
  int row = blockIdx.x * 4 + (threadIdx.x >> 6);
  if (row >= NODES) return;
  int lane = threadIdx.x & 63, half = lane >> 5, l32 = lane & 31;
  const int* ro = rowoff + r * (NODES + 1);
  int o0 = ro[row], o1 = ro[row + 1];
  const int* lst = csr + (size_t)r * EDGES;
  float acc[8] = {};
  for (int j = o0 + half; j < o1; j += 2) {
    int sidx = lst[j];
    u16x8 v = *(const u16x8*)(src + (size_t)sidx * 1024 + l32 * 8);
#pragma unroll
    for (int e = 0; e < 8; ++e) acc[e] += bf2f(v[e]);
  }
#pragma unroll
  for (int e = 0; e < 8; ++e) acc[e] += __shfl_xor(acc[e], 32);
  if (half == 0) {
    int deg = o1 - o0;
    float inv = deg ? 1.f / (float)deg : 0.f;
    u16x8 o;
#pragma unroll
    for (int e = 0; e < 8; ++e) o[e] = f2bf(acc[e] * inv);
    *(u16x8*)(dst + (size_t)row * 1024 + l32 * 8) = o;
  }
}

// ---------------- MFMA bf16 GEMM: C[20000 x 256] = A[20000 x K] @ Bt[256 x K]^T + bias ----
// BM=128 BN=64 BK=32. OUTMODE 0: fp32 raw (stride 256) + BN stats atomics
//                     OUTMODE 1: bf16 out (stride 1024)
template <int K, int OUTMODE>
__global__ __launch_bounds__(256) void k_mfma(const unsigned short* __restrict__ A,
                                              const unsigned short* __restrict__ Bt,
                                              const float* __restrict__ bias,
                                              float* __restrict__ Craw,
                                              unsigned short* __restrict__ Cbf,
                                              float* __restrict__ stats) {
  __shared__ unsigned short As[128 * 32];
  __shared__ unsigned short Bs[64 * 32];
  const int bm = blockIdx.x * 128, bn = blockIdx.y * 64;
  const int tid = threadIdx.x, lane = tid & 63, w = tid >> 6;
  const int wr = w >> 1, wc = w & 1;
  // staging: thread t covers tile row sr, byte chunk soff (pre-swizzled source)
  const int sr = tid >> 2;
  const int soff = (tid & 3) * 16;
  const int swz = soff ^ ((sr & 6) << 3);
  int r0 = bm + sr;       if (r0 >= NODES) r0 = NODES - 1;
  int r1 = bm + 64 + sr;  if (r1 >= NODES) r1 = NODES - 1;
  const char* gA0 = (const char*)A + (size_t)r0 * K * 2 + swz;
  const char* gA1 = (const char*)A + (size_t)r1 * K * 2 + swz;
  const char* gB  = (const char*)Bt + (size_t)(bn + sr) * K * 2 + swz;
  char* lA0 = (char*)As + w * 1024;
  char* lA1 = (char*)As + 4096 + w * 1024;
  char* lB  = (char*)Bs + w * 1024;

  f32x4 acc[4][2] = {};
  const int kb = (lane >> 4) * 16;  // byte offset of this lane's k-chunk

  for (int k0 = 0; k0 < K; k0 += 32) {
    GLDS(gA0 + 2 * k0, lA0);
    GLDS(gA1 + 2 * k0, lA1);
    GLDS(gB + 2 * k0, lB);
    __syncthreads();
    bf16x8 bfr[2];
#pragma unroll
    for (int n = 0; n < 2; ++n) {
      int rowb = wc * 32 + n * 16 + (lane & 15);
      int off = kb ^ ((rowb & 6) << 3);
      bfr[n] = *(const bf16x8*)(Bs + rowb * 32 + (off >> 1));
    }
#pragma unroll
    for (int m = 0; m < 4; ++m) {
      int rowa = wr * 64 + m * 16 + (lane & 15);
      int off = kb ^ ((rowa & 6) << 3);
      bf16x8 afr = *(const bf16x8*)(As + rowa * 32 + (off >> 1));
      acc[m][0] = __builtin_amdgcn_mfma_f32_16x16x32_bf16(afr, bfr[0], acc[m][0], 0, 0, 0);
      acc[m][1] = __builtin_amdgcn_mfma_f32_16x16x32_bf16(afr, bfr[1], acc[m][1], 0, 0, 0);
    }
    __syncthreads();
  }

  // epilogue: C col = bn + wc*32 + n*16 + (lane&15); row = bm + wr*64 + m*16 + (lane>>4)*4 + q
#pragma unroll
  for (int n = 0; n < 2; ++n) {
    int col = bn + wc * 32 + n * 16 + (lane & 15);
    float bv = bias[col];
    float s = 0.f, s2 = 0.f;
#pragma unroll
    for (int m = 0; m < 4; ++m) {
#pragma unroll
      for (int q = 0; q < 4; ++q) {
        int row = bm + wr * 64 + m * 16 + ((lane >> 4) * 4) + q;
        if (row < NODES) {
          float v = acc[m][n][q] + bv;
          if (OUTMODE == 0) {
            Craw[(size_t)row * 256 + col] = v;
            s += v;
            s2 = fmaf(v, v, s2);
          } else {
            Cbf[(size_t)row * 1024 + col] = f2bf(v);
          }
        }
      }
    }
    if (OUTMODE == 0) {
      s += __shfl_xor(s, 16);
      s += __shfl_xor(s, 32);
      s2 += __shfl_xor(s2, 16);
      s2 += __shfl_xor(s2, 32);
      if (lane < 16) {
        atomicAdd(&stats[col], s);
        atomicAdd(&stats[256 + col], s2);
      }
    }
  }
}

// ---------------- BN apply (layer 0): raw fp32 -> bf16 xs slice ----------------
__global__ __launch_bounds__(256) void k_bnapply(const float* __restrict__ raw,
                                                 const float* __restrict__ stats,
                                                 const float* __restrict__ gamma,
                                                 const float* __restrict__ beta,
                                                 unsigned short* __restrict__ out) {
  int idx = blockIdx.x * 256 + threadIdx.x;
  if (idx >= NODES * 256) return;
  int c = idx & 255;
  int rrow = idx >> 8;
  const float inv3 = 1.f / 3.f;
  float m = stats[c] * (inv3 / NODES);
  float ex2 = stats[256 + c] * (inv3 * inv3 / NODES);
  float var = ex2 - m * m;
  float v = (raw[idx] * inv3 - m) * rsqrtf(var + 1e-5f) * gamma[c] + beta[c];
  out[(size_t)rrow * 1024 + c] = f2bf(fmaxf(v, 0.f));
}

// ---------------- pooling (fused layer-1 BN+relu+residual) ----------------
__global__ __launch_bounds__(256) void k_pool(const float* __restrict__ raw,
                                              const float* __restrict__ stats,
                                              const float* __restrict__ gamma,
                                              const float* __restrict__ beta,
                                              const unsigned short* __restrict__ prev,
                                              const int* __restrict__ batch,
                                              float* __restrict__ pooled,
                                              float* __restrict__ gcnt) {
  int c = threadIdx.x;
  int rows_per = (NODES + gridDim.x - 1) / gridDim.x;
  int r0 = blockIdx.x * rows_per;
  int r1 = min(NODES, r0 + rows_per);
  if (r0 >= NODES) return;
  const float inv3 = 1.f / 3.f;
  float m = stats[c] * (inv3 / NODES);
  float ex2 = stats[256 + c] * (inv3 * inv3 / NODES);
  float rs = rsqrtf(ex2 - m * m + 1e-5f) * gamma[c];
  float bt = beta[c];
  float s = 0.f;
  int curg = batch[r0];
  for (int r = r0; r < r1; ++r) {
    int g = batch[r];
    if (g != curg) {
      atomicAdd(&pooled[curg * 256 + c], s);
      s = 0.f;
      curg = g;
    }
    float v = fmaxf((raw[(size_t)r * 256 + c] * inv3 - m) * rs + bt, 0.f) +
              bf2f(prev[(size_t)r * 1024 + c]);
    s += v;
  }
  atomicAdd(&pooled[curg * 256 + c], s);
  if (c == 0) {
    int cn = 0;
    int cg = batch[r0];
    for (int r = r0; r < r1; ++r) {
      int g = batch[r];
      if (g != cg) {
        atomicAdd(&gcnt[cg], (float)cn);
        cn = 0;
        cg = g;
      }
      cn++;
    }
    atomicAdd(&gcnt[cg], (float)cn);
  }
}

__global__ __launch_bounds__(256) void k_final(const float* __restrict__ pooled,
                                               const float* __restrict__ gcnt,
                                               const float* __restrict__ Wout,
                                               const float* __restrict__ bout,
                                               float* __restrict__ out) {
  int g = blockIdx.x;
  int h = threadIdx.x;
  float cv = fmaxf(gcnt[g], 1.f);
  float cp = fmaxf(gcnt[NGRAPH + g], 1.f);
  float v = pooled[g * 256 + h] / cv * Wout[h] +
            pooled[NGRAPH * 256 + g * 256 + h] / cp * Wout[256 + h];
#pragma unroll
  for (int s = 32; s > 0; s >>= 1) v += __shfl_down(v, s, 64);
  __shared__ float sh[4];
  if ((h & 63) == 0) sh[h >> 6] = v;
  __syncthreads();
  if (h == 0) {
    float t = sh[0] + sh[1] + sh[2] + sh[3] + bout[0];
    out[g] = 1.f / (1.f + expf(-t));
  }
}

// ---------------- host ----------------
extern "C" void kernel_launch(void* const* d_in, const int* in_sizes, int n_in,
                              void* d_out, int out_size, void* d_ws, size_t ws_size,
                              hipStream_t stream) {
  const float* x_vuln = (const float*)d_in[0];
  const float* x_patch = (const float*)d_in[1];
  const float* W_emb = (const float*)d_in[2];
  const float* b_emb = (const float*)d_in[3];
  const float* W_l = (const float*)d_in[4];
  const float* b_l = (const float*)d_in[5];
  const float* W_r = (const float*)d_in[6];
  const float* gamma = (const float*)d_in[7];
  const float* beta = (const float*)d_in[8];
  const float* W_out = (const float*)d_in[9];
  const float* b_out = (const float*)d_in[10];
  const int* edge_index = (const int*)d_in[11];
  const int* batch_vuln = (const int*)d_in[12];
  const int* batch_patch = (const int*)d_in[13];

  char* ws = (char*)d_ws;
  size_t off = 0;
  auto alloc = [&](size_t bytes) -> void* {
    void* p = ws + off;
    off = (off + bytes + 255) & ~(size_t)255;
    return p;
  };
  int* csr = (int*)alloc((size_t)NREL * EDGES * 4);
  int* rowoff = (int*)alloc((size_t)NREL * (NODES + 1) * 4);
  int* cnt = (int*)alloc((size_t)NREL * NODES * 4);
  int* cur = (int*)alloc((size_t)NREL * NODES * 4);
  unsigned short* Acat[2];
  Acat[0] = (unsigned short*)alloc((size_t)NODES * 1024 * 2);
  Acat[1] = (unsigned short*)alloc((size_t)NODES * 1024 * 2);
  float* raw[2];
  raw[0] = (float*)alloc((size_t)NODES * 256 * 4);
  raw[1] = (float*)alloc((size_t)NODES * 256 * 4);
  unsigned short* xbf = (unsigned short*)alloc((size_t)2 * NODES * DIN * 2);
  unsigned short* Wt = (unsigned short*)alloc((size_t)4 * 256 * 1024 * 2);
  unsigned short* Wet = (unsigned short*)alloc((size_t)2 * 256 * DIN * 2);
  float* bsum = (float*)alloc(512 * 4);
  float* stats = (float*)alloc(1024 * 4);  // [dt][{sum,sumsq}][256]
  float* pooled = (float*)alloc((size_t)2 * NGRAPH * 256 * 4);
  float* gcnt = (float*)alloc((size_t)2 * NGRAPH * 4);

  hipMemsetAsync(cnt, 0, (size_t)NREL * NODES * 4, stream);
  hipMemsetAsync(cur, 0, (size_t)NREL * NODES * 4, stream);
  hipMemsetAsync(pooled, 0, (size_t)2 * NGRAPH * 256 * 4, stream);
  hipMemsetAsync(gcnt, 0, (size_t)2 * NGRAPH * 4, stream);

  int tot_e = NREL * EDGES;
  k_hist<<<(tot_e + 255) / 256, 256, 0, stream>>>(edge_index, cnt);
  k_scan<<<NREL, 1024, 0, stream>>>(cnt, rowoff);
  k_scatter<<<(tot_e + 255) / 256, 256, 0, stream>>>(edge_index, rowoff, cur, csr);

  k_xcvt<<<(2 * NODES * DIN + 255) / 256, 256, 0, stream>>>(x_vuln, x_patch, xbf);
  k_wtrans<<<dim3(64, 16, 4), dim3(16, 16), 0, stream>>>(W_l, W_r, Wt);
  k_wembt<<<dim3(8, 16, 2), dim3(16, 16), 0, stream>>>(W_emb, Wet);

  dim3 ggrid(157, 4);
  // embed: xs0 -> Acat[t] seg3
  for (int t = 0; t < 2; ++t)
    k_mfma<DIN, 1><<<ggrid, 256, 0, stream>>>(xbf + (size_t)t * NODES * DIN,
                                              Wet + (size_t)t * 256 * DIN,
                                              b_emb + t * 256, nullptr,
                                              Acat[t] + 768, nullptr);

  for (int layer = 0; layer < 2; ++layer) {
    k_bsum<<<4, 256, 0, stream>>>(b_l, bsum, stats, layer);
    k_agg<<<dim3(5000, 3, 2), 256, 0, stream>>>(Acat[0], Acat[1], rowoff, csr);
    for (int dt = 0; dt < 2; ++dt)
      k_mfma<1024, 0><<<ggrid, 256, 0, stream>>>(
          Acat[dt], Wt + (size_t)(layer * 2 + dt) * 256 * 1024, bsum + dt * 256,
          raw[dt], nullptr, stats + dt * 512);
    if (layer == 0) {
      for (int dt = 0; dt < 2; ++dt)
        k_bnapply<<<(NODES * 256 + 255) / 256, 256, 0, stream>>>(
            raw[dt], stats + dt * 512, gamma + (layer * 2 + dt) * 256,
            beta + (layer * 2 + dt) * 256, Acat[dt] + 768);
    }
  }

  k_pool<<<64, 256, 0, stream>>>(raw[0], stats, gamma + 2 * 256, beta + 2 * 256,
                                 Acat[0] + 768, batch_vuln, pooled, gcnt);
  k_pool<<<64, 256, 0, stream>>>(raw[1], stats + 512, gamma + 3 * 256, beta + 3 * 256,
                                 Acat[1] + 768, batch_patch, pooled + NGRAPH * 256,
                                 gcnt + NGRAPH);
  k_final<<<NGRAPH, 256, 0, stream>>>(pooled, gcnt, W_out, b_out, (float*)d_out);
}

// Round 3
// 772.745 us; speedup vs baseline: 2.6938x; 1.1606x over previous
//
#include <hip/hip_runtime.h>
#include <math.h>

#define NODES 20000
#define EDGES 320000
#define DIN 128
#define HID 256
#define NGRAPH 32
#define NREL 6

typedef __attribute__((ext_vector_type(8))) short bf16x8;
typedef __attribute__((ext_vector_type(8))) unsigned short u16x8;
typedef __attribute__((ext_vector_type(4))) unsigned short u16x4;
typedef __attribute__((ext_vector_type(4))) float f32x4;

__device__ __forceinline__ float bf2f(unsigned short u) {
  return __uint_as_float(((unsigned)u) << 16);
}
__device__ __forceinline__ unsigned short f2bf(float f) {
  unsigned u = __float_as_uint(f);
  unsigned r = (u + 0x7fffu + ((u >> 16) & 1u)) >> 16;
  return (unsigned short)r;
}

#define GLDS(g, l)                                                            \
  __builtin_amdgcn_global_load_lds(                                           \
      (const __attribute__((address_space(1))) void*)(g),                     \
      (__attribute__((address_space(3))) void*)(l), 16, 0, 0)

// ---------------- CSR build ----------------
__global__ void k_hist(const int* __restrict__ edges, int* __restrict__ cnt) {
  int idx = blockIdx.x * blockDim.x + threadIdx.x;
  if (idx >= NREL * EDGES) return;
  int r = idx / EDGES;
  int e = idx - r * EDGES;
  int dst = edges[(r * 2 + 1) * EDGES + e];
  atomicAdd(&cnt[r * NODES + dst], 1);
}

__global__ __launch_bounds__(1024) void k_scan(const int* __restrict__ cnt,
                                               int* __restrict__ rowoff) {
  int r = blockIdx.x;
  __shared__ int wsum[16];
  int lane = threadIdx.x & 63, wid = threadIdx.x >> 6;
  int running = 0;
  for (int base = 0; base < NODES; base += 1024) {
    int i = base + threadIdx.x;
    int v = (i < NODES) ? cnt[r * NODES + i] : 0;
    int x = v;
#pragma unroll
    for (int s = 1; s < 64; s <<= 1) {
      int t = __shfl_up(x, s, 64);
      if (lane >= s) x += t;
    }
    if (lane == 63) wsum[wid] = x;
    __syncthreads();
    if (threadIdx.x < 16) {
      int w = wsum[threadIdx.x];
#pragma unroll
      for (int s = 1; s < 16; s <<= 1) {
        int t = __shfl_up(w, s, 16);
        if ((threadIdx.x & 15) >= s) w += t;
      }
      wsum[threadIdx.x] = w;  // inclusive wave-sums
    }
    __syncthreads();
    int wexcl = (wid == 0) ? 0 : wsum[wid - 1];
    if (i < NODES) rowoff[r * (NODES + 1) + i] = running + wexcl + x - v;
    int tot = wsum[15];
    __syncthreads();
    running += tot;
  }
  if (threadIdx.x == 0) rowoff[r * (NODES + 1) + NODES] = running;
}

__global__ void k_scatter(const int* __restrict__ edges, const int* __restrict__ rowoff,
                          int* __restrict__ cur, int* __restrict__ csr) {
  int idx = blockIdx.x * blockDim.x + threadIdx.x;
  if (idx >= NREL * EDGES) return;
  int r = idx / EDGES;
  int e = idx - r * EDGES;
  int src = edges[(r * 2 + 0) * EDGES + e];
  int dst = edges[(r * 2 + 1) * EDGES + e];
  int p = atomicAdd(&cur[r * NODES + dst], 1);
  csr[r * EDGES + rowoff[r * (NODES + 1) + dst] + p] = src;
}

// ---------------- prep: x -> bf16 (vectorized) ----------------
__global__ void k_xcvt(const float* __restrict__ xv, const float* __restrict__ xp,
                       unsigned short* __restrict__ xbf) {
  int idx = blockIdx.x * 256 + threadIdx.x;  // group of 4 elems
  const int ND = NODES * DIN;
  int e0 = idx * 4;
  if (e0 >= 2 * ND) return;
  const float* s = (e0 < ND) ? (xv + e0) : (xp + e0 - ND);
  float4 v = *(const float4*)s;
  u16x4 o;
  o[0] = f2bf(v.x);
  o[1] = f2bf(v.y);
  o[2] = f2bf(v.z);
  o[3] = f2bf(v.w);
  *(u16x4*)(xbf + e0) = o;
}

// ---------------- prep: weight concat transpose -> bf16 ----------------
__global__ void k_wtrans(const float* __restrict__ W_l, const float* __restrict__ W_r,
                         unsigned short* __restrict__ Wt) {
  const int rels[2][3] = {{0, 1, 3}, {2, 4, 5}};
  int kt = blockIdx.x, nt = blockIdx.y, ld = blockIdx.z;
  int layer = ld >> 1, dt = ld & 1;
  __shared__ float sh[16][17];
  int k0 = kt * 16, n0 = nt * 16;
  int seg = k0 >> 8, kk0 = k0 & 255;
  int tx = threadIdx.x, ty = threadIdx.y;
  float v;
  if (seg < 3) {
    v = W_l[(((size_t)layer * NREL + rels[dt][seg]) * HID + kk0 + ty) * HID + n0 + tx];
  } else {
    v = 0.f;
    for (int j = 0; j < 3; ++j)
      v += W_r[(((size_t)layer * NREL + rels[dt][j]) * HID + kk0 + ty) * HID + n0 + tx];
  }
  sh[ty][tx] = v;
  __syncthreads();
  Wt[((size_t)ld * HID + n0 + ty) * 1024 + k0 + tx] = f2bf(sh[tx][ty]);
}

__global__ void k_wembt(const float* __restrict__ W_emb, unsigned short* __restrict__ Wet) {
  int kt = blockIdx.x, nt = blockIdx.y, t = blockIdx.z;
  __shared__ float sh[16][17];
  int k0 = kt * 16, n0 = nt * 16;
  int tx = threadIdx.x, ty = threadIdx.y;
  sh[ty][tx] = W_emb[((size_t)t * DIN + k0 + ty) * HID + n0 + tx];
  __syncthreads();
  Wet[((size_t)t * HID + n0 + ty) * DIN + k0 + tx] = f2bf(sh[tx][ty]);
}

__global__ void k_bsum(const float* __restrict__ b_l, float* __restrict__ bsum,
                       float* __restrict__ stats, int layer) {
  const int rels[2][3] = {{0, 1, 3}, {2, 4, 5}};
  int idx = blockIdx.x * 256 + threadIdx.x;
  if (idx < 512) {
    int dt = idx >> 8, c = idx & 255;
    float s = 0.f;
    for (int j = 0; j < 3; ++j) s += b_l[(layer * NREL + rels[dt][j]) * HID + c];
    bsum[idx] = s;
  }
  if (idx < 1024) stats[idx] = 0.f;
}

// ---------------- fused aggregation, XCD column-partitioned ----------------
// grid (8, 157, 3): x = st*4 + chunk (chunk = 128B = 64 cols), y = row block (128 rows),
// z = relation index within src type. gridDim.x==8 => blockIdx.x == XCD (round-robin
// heuristic): per-XCD gather working set = 20000 rows * 128B * 1 type = 2.5MB < 4MB L2.
__global__ __launch_bounds__(256) void k_agg(unsigned short* __restrict__ a0,
                                             unsigned short* __restrict__ a1,
                                             const int* __restrict__ rowoff,
                                             const int* __restrict__ csr) {
  const int dt_of[6] = {0, 0, 1, 0, 1, 1};
  const int seg_of[6] = {0, 1, 0, 2, 1, 2};
  int x = blockIdx.x;
  int st = x >> 2, chunk = x & 3;
  int rel = st * 3 + blockIdx.z;
  int dt = dt_of[rel], seg = seg_of[rel];
  const unsigned short* src = (st == 0 ? a0 : a1) + 768 + chunk * 64;  // xs slice
  unsigned short* dst = (dt == 0 ? a0 : a1) + seg * 256 + chunk * 64;
  int lane16 = threadIdx.x & 15;  // 8B column unit within 128B chunk
  int rsub = threadIdx.x >> 4;    // 0..15
  const int* ro = rowoff + rel * (NODES + 1);
  const int* lst = csr + (size_t)rel * EDGES;
  int rbase = blockIdx.y * 128;
#pragma unroll 1
  for (int pass = 0; pass < 8; ++pass) {
    int row = rbase + pass * 16 + rsub;
    if (row >= NODES) break;
    int o0 = ro[row], o1 = ro[row + 1];
    float acc0[4] = {}, acc1[4] = {};
    int j = o0;
    for (; j + 1 < o1; j += 2) {
      int s0 = lst[j], s1 = lst[j + 1];
      u16x4 v0 = *(const u16x4*)(src + (size_t)s0 * 1024 + lane16 * 4);
      u16x4 v1 = *(const u16x4*)(src + (size_t)s1 * 1024 + lane16 * 4);
#pragma unroll
      for (int e = 0; e < 4; ++e) {
        acc0[e] += bf2f(v0[e]);
        acc1[e] += bf2f(v1[e]);
      }
    }
    if (j < o1) {
      int s0 = lst[j];
      u16x4 v0 = *(const u16x4*)(src + (size_t)s0 * 1024 + lane16 * 4);
#pragma unroll
      for (int e = 0; e < 4; ++e) acc0[e] += bf2f(v0[e]);
    }
    int deg = o1 - o0;
    float inv = deg ? 1.f / (float)deg : 0.f;
    u16x4 o;
#pragma unroll
    for (int e = 0; e < 4; ++e) o[e] = f2bf((acc0[e] + acc1[e]) * inv);
    *(u16x4*)(dst + (size_t)row * 1024 + lane16 * 4) = o;
  }
}

// ---------------- MFMA bf16 GEMM ----------------
template <int K, int OUTMODE>
__global__ __launch_bounds__(256) void k_mfma(const unsigned short* __restrict__ A,
                                              const unsigned short* __restrict__ Bt,
                                              const float* __restrict__ bias,
                                              float* __restrict__ Craw,
                                              unsigned short* __restrict__ Cbf,
                                              float* __restrict__ stats) {
  __shared__ unsigned short As[128 * 32];
  __shared__ unsigned short Bs[64 * 32];
  const int bm = blockIdx.x * 128, bn = blockIdx.y * 64;
  const int tid = threadIdx.x, lane = tid & 63, w = tid >> 6;
  const int wr = w >> 1, wc = w & 1;
  const int sr = tid >> 2;
  const int soff = (tid & 3) * 16;
  const int swz = soff ^ ((sr & 6) << 3);
  int r0 = bm + sr;       if (r0 >= NODES) r0 = NODES - 1;
  int r1 = bm + 64 + sr;  if (r1 >= NODES) r1 = NODES - 1;
  const char* gA0 = (const char*)A + (size_t)r0 * K * 2 + swz;
  const char* gA1 = (const char*)A + (size_t)r1 * K * 2 + swz;
  const char* gB  = (const char*)Bt + (size_t)(bn + sr) * K * 2 + swz;
  char* lA0 = (char*)As + w * 1024;
  char* lA1 = (char*)As + 4096 + w * 1024;
  char* lB  = (char*)Bs + w * 1024;

  f32x4 acc[4][2] = {};
  const int kb = (lane >> 4) * 16;

  for (int k0 = 0; k0 < K; k0 += 32) {
    GLDS(gA0 + 2 * k0, lA0);
    GLDS(gA1 + 2 * k0, lA1);
    GLDS(gB + 2 * k0, lB);
    __syncthreads();
    bf16x8 bfr[2];
#pragma unroll
    for (int n = 0; n < 2; ++n) {
      int rowb = wc * 32 + n * 16 + (lane & 15);
      int off = kb ^ ((rowb & 6) << 3);
      bfr[n] = *(const bf16x8*)(Bs + rowb * 32 + (off >> 1));
    }
#pragma unroll
    for (int m = 0; m < 4; ++m) {
      int rowa = wr * 64 + m * 16 + (lane & 15);
      int off = kb ^ ((rowa & 6) << 3);
      bf16x8 afr = *(const bf16x8*)(As + rowa * 32 + (off >> 1));
      acc[m][0] = __builtin_amdgcn_mfma_f32_16x16x32_bf16(afr, bfr[0], acc[m][0], 0, 0, 0);
      acc[m][1] = __builtin_amdgcn_mfma_f32_16x16x32_bf16(afr, bfr[1], acc[m][1], 0, 0, 0);
    }
    __syncthreads();
  }

#pragma unroll
  for (int n = 0; n < 2; ++n) {
    int col = bn + wc * 32 + n * 16 + (lane & 15);
    float bv = bias[col];
    float s = 0.f, s2 = 0.f;
#pragma unroll
    for (int m = 0; m < 4; ++m) {
#pragma unroll
      for (int q = 0; q < 4; ++q) {
        int row = bm + wr * 64 + m * 16 + ((lane >> 4) * 4) + q;
        if (row < NODES) {
          float v = acc[m][n][q] + bv;
          if (OUTMODE == 0) {
            Craw[(size_t)row * 256 + col] = v;
            s += v;
            s2 = fmaf(v, v, s2);
          } else {
            Cbf[(size_t)row * 1024 + col] = f2bf(v);
          }
        }
      }
    }
    if (OUTMODE == 0) {
      s += __shfl_xor(s, 16);
      s += __shfl_xor(s, 32);
      s2 += __shfl_xor(s2, 16);
      s2 += __shfl_xor(s2, 32);
      if (lane < 16) {
        atomicAdd(&stats[col], s);
        atomicAdd(&stats[256 + col], s2);
      }
    }
  }
}

// ---------------- BN apply (layer 0): raw fp32 -> bf16 xs slice ----------------
__global__ __launch_bounds__(256) void k_bnapply(const float* __restrict__ raw,
                                                 const float* __restrict__ stats,
                                                 const float* __restrict__ gamma,
                                                 const float* __restrict__ beta,
                                                 unsigned short* __restrict__ out) {
  int idx = blockIdx.x * 256 + threadIdx.x;
  if (idx >= NODES * 256) return;
  int c = idx & 255;
  int rrow = idx >> 8;
  const float inv3 = 1.f / 3.f;
  float m = stats[c] * (inv3 / NODES);
  float ex2 = stats[256 + c] * (inv3 * inv3 / NODES);
  float var = ex2 - m * m;
  float v = (raw[idx] * inv3 - m) * rsqrtf(var + 1e-5f) * gamma[c] + beta[c];
  out[(size_t)rrow * 1024 + c] = f2bf(fmaxf(v, 0.f));
}

// ---------------- pooling (fused layer-1 BN+relu+residual) ----------------
__global__ __launch_bounds__(256) void k_pool(const float* __restrict__ raw,
                                              const float* __restrict__ stats,
                                              const float* __restrict__ gamma,
                                              const float* __restrict__ beta,
                                              const unsigned short* __restrict__ prev,
                                              const int* __restrict__ batch,
                                              float* __restrict__ pooled,
                                              float* __restrict__ gcnt) {
  int c = threadIdx.x;
  int rows_per = (NODES + gridDim.x - 1) / gridDim.x;
  int r0 = blockIdx.x * rows_per;
  int r1 = min(NODES, r0 + rows_per);
  if (r0 >= NODES) return;
  const float inv3 = 1.f / 3.f;
  float m = stats[c] * (inv3 / NODES);
  float ex2 = stats[256 + c] * (inv3 * inv3 / NODES);
  float rs = rsqrtf(ex2 - m * m + 1e-5f) * gamma[c];
  float bt = beta[c];
  float s = 0.f;
  int curg = batch[r0];
  for (int r = r0; r < r1; ++r) {
    int g = batch[r];
    if (g != curg) {
      atomicAdd(&pooled[curg * 256 + c], s);
      s = 0.f;
      curg = g;
    }
    float v = fmaxf((raw[(size_t)r * 256 + c] * inv3 - m) * rs + bt, 0.f) +
              bf2f(prev[(size_t)r * 1024 + c]);
    s += v;
  }
  atomicAdd(&pooled[curg * 256 + c], s);
  if (c == 0) {
    int cn = 0;
    int cg = batch[r0];
    for (int r = r0; r < r1; ++r) {
      int g = batch[r];
      if (g != cg) {
        atomicAdd(&gcnt[cg], (float)cn);
        cn = 0;
        cg = g;
      }
      cn++;
    }
    atomicAdd(&gcnt[cg], (float)cn);
  }
}

__global__ __launch_bounds__(256) void k_final(const float* __restrict__ pooled,
                                               const float* __restrict__ gcnt,
                                               const float* __restrict__ Wout,
                                               const float* __restrict__ bout,
                                               float* __restrict__ out) {
  int g = blockIdx.x;
  int h = threadIdx.x;
  float cv = fmaxf(gcnt[g], 1.f);
  float cp = fmaxf(gcnt[NGRAPH + g], 1.f);
  float v = pooled[g * 256 + h] / cv * Wout[h] +
            pooled[NGRAPH * 256 + g * 256 + h] / cp * Wout[256 + h];
#pragma unroll
  for (int s = 32; s > 0; s >>= 1) v += __shfl_down(v, s, 64);
  __shared__ float sh[4];
  if ((h & 63) == 0) sh[h >> 6] = v;
  __syncthreads();
  if (h == 0) {
    float t = sh[0] + sh[1] + sh[2] + sh[3] + bout[0];
    out[g] = 1.f / (1.f + expf(-t));
  }
}

// ---------------- host ----------------
extern "C" void kernel_launch(void* const* d_in, const int* in_sizes, int n_in,
                              void* d_out, int out_size, void* d_ws, size_t ws_size,
                              hipStream_t stream) {
  const float* x_vuln = (const float*)d_in[0];
  const float* x_patch = (const float*)d_in[1];
  const float* W_emb = (const float*)d_in[2];
  const float* b_emb = (const float*)d_in[3];
  const float* W_l = (const float*)d_in[4];
  const float* b_l = (const float*)d_in[5];
  const float* W_r = (const float*)d_in[6];
  const float* gamma = (const float*)d_in[7];
  const float* beta = (const float*)d_in[8];
  const float* W_out = (const float*)d_in[9];
  const float* b_out = (const float*)d_in[10];
  const int* edge_index = (const int*)d_in[11];
  const int* batch_vuln = (const int*)d_in[12];
  const int* batch_patch = (const int*)d_in[13];

  char* ws = (char*)d_ws;
  size_t off = 0;
  auto alloc = [&](size_t bytes) -> void* {
    void* p = ws + off;
    off = (off + bytes + 255) & ~(size_t)255;
    return p;
  };
  int* csr = (int*)alloc((size_t)NREL * EDGES * 4);
  int* rowoff = (int*)alloc((size_t)NREL * (NODES + 1) * 4);
  int* cnt = (int*)alloc((size_t)NREL * NODES * 4);
  int* cur = (int*)alloc((size_t)NREL * NODES * 4);
  unsigned short* Acat[2];
  Acat[0] = (unsigned short*)alloc((size_t)NODES * 1024 * 2);
  Acat[1] = (unsigned short*)alloc((size_t)NODES * 1024 * 2);
  float* raw[2];
  raw[0] = (float*)alloc((size_t)NODES * 256 * 4);
  raw[1] = (float*)alloc((size_t)NODES * 256 * 4);
  unsigned short* xbf = (unsigned short*)alloc((size_t)2 * NODES * DIN * 2);
  unsigned short* Wt = (unsigned short*)alloc((size_t)4 * 256 * 1024 * 2);
  unsigned short* Wet = (unsigned short*)alloc((size_t)2 * 256 * DIN * 2);
  float* bsum = (float*)alloc(512 * 4);
  float* stats = (float*)alloc(1024 * 4);
  float* pooled = (float*)alloc((size_t)2 * NGRAPH * 256 * 4);
  float* gcnt = (float*)alloc((size_t)2 * NGRAPH * 4);

  hipMemsetAsync(cnt, 0, (size_t)NREL * NODES * 4, stream);
  hipMemsetAsync(cur, 0, (size_t)NREL * NODES * 4, stream);
  hipMemsetAsync(pooled, 0, (size_t)2 * NGRAPH * 256 * 4, stream);
  hipMemsetAsync(gcnt, 0, (size_t)2 * NGRAPH * 4, stream);

  int tot_e = NREL * EDGES;
  k_hist<<<(tot_e + 255) / 256, 256, 0, stream>>>(edge_index, cnt);
  k_scan<<<NREL, 1024, 0, stream>>>(cnt, rowoff);
  k_scatter<<<(tot_e + 255) / 256, 256, 0, stream>>>(edge_index, rowoff, cur, csr);

  k_xcvt<<<(2 * NODES * DIN / 4 + 255) / 256, 256, 0, stream>>>(x_vuln, x_patch, xbf);
  k_wtrans<<<dim3(64, 16, 4), dim3(16, 16), 0, stream>>>(W_l, W_r, Wt);
  k_wembt<<<dim3(8, 16, 2), dim3(16, 16), 0, stream>>>(W_emb, Wet);

  dim3 ggrid(157, 4);
  for (int t = 0; t < 2; ++t)
    k_mfma<DIN, 1><<<ggrid, 256, 0, stream>>>(xbf + (size_t)t * NODES * DIN,
                                              Wet + (size_t)t * 256 * DIN,
                                              b_emb + t * 256, nullptr,
                                              Acat[t] + 768, nullptr);

  for (int layer = 0; layer < 2; ++layer) {
    k_bsum<<<4, 256, 0, stream>>>(b_l, bsum, stats, layer);
    k_agg<<<dim3(8, 157, 3), 256, 0, stream>>>(Acat[0], Acat[1], rowoff, csr);
    for (int dt = 0; dt < 2; ++dt)
      k_mfma<1024, 0><<<ggrid, 256, 0, stream>>>(
          Acat[dt], Wt + (size_t)(layer * 2 + dt) * 256 * 1024, bsum + dt * 256,
          raw[dt], nullptr, stats + dt * 512);
    if (layer == 0) {
      for (int dt = 0; dt < 2; ++dt)
        k_bnapply<<<(NODES * 256 + 255) / 256, 256, 0, stream>>>(
            raw[dt], stats + dt * 512, gamma + (layer * 2 + dt) * 256,
            beta + (layer * 2 + dt) * 256, Acat[dt] + 768);
    }
  }

  k_pool<<<128, 256, 0, stream>>>(raw[0], stats, gamma + 2 * 256, beta + 2 * 256,
                                  Acat[0] + 768, batch_vuln, pooled, gcnt);
  k_pool<<<128, 256, 0, stream>>>(raw[1], stats + 512, gamma + 3 * 256, beta + 3 * 256,
                                  Acat[1] + 768, batch_patch, pooled + NGRAPH * 256,
                                  gcnt + NGRAPH);
  k_final<<<NGRAPH, 256, 0, stream>>>(pooled, gcnt, W_out, b_out, (float*)d_out);
}

// Round 4
// 746.191 us; speedup vs baseline: 2.7896x; 1.0356x over previous
//
#include <hip/hip_runtime.h>
#include <math.h>

#define NODES 20000
#define EDGES 320000
#define DIN 128
#define HID 256
#define NGRAPH 32
#define NREL 6

typedef __attribute__((ext_vector_type(8))) short bf16x8;
typedef __attribute__((ext_vector_type(8))) unsigned short u16x8;
typedef __attribute__((ext_vector_type(4))) unsigned short u16x4;
typedef __attribute__((ext_vector_type(4))) float f32x4;

__device__ __forceinline__ float bf2f(unsigned short u) {
  return __uint_as_float(((unsigned)u) << 16);
}
__device__ __forceinline__ unsigned short f2bf(float f) {
  unsigned u = __float_as_uint(f);
  unsigned r = (u + 0x7fffu + ((u >> 16) & 1u)) >> 16;
  return (unsigned short)r;
}

#define GLDS(g, l)                                                            \
  __builtin_amdgcn_global_load_lds(                                           \
      (const __attribute__((address_space(1))) void*)(g),                     \
      (__attribute__((address_space(3))) void*)(l), 16, 0, 0)

// ---------------- CSR build ----------------
__global__ void k_hist(const int* __restrict__ edges, int* __restrict__ cnt) {
  int idx = blockIdx.x * blockDim.x + threadIdx.x;
  if (idx >= NREL * EDGES) return;
  int r = idx / EDGES;
  int e = idx - r * EDGES;
  int dst = edges[(r * 2 + 1) * EDGES + e];
  atomicAdd(&cnt[r * NODES + dst], 1);
}

__global__ __launch_bounds__(1024) void k_scan(const int* __restrict__ cnt,
                                               int* __restrict__ rowoff) {
  int r = blockIdx.x;
  __shared__ int wsum[16];
  int lane = threadIdx.x & 63, wid = threadIdx.x >> 6;
  int running = 0;
  for (int base = 0; base < NODES; base += 1024) {
    int i = base + threadIdx.x;
    int v = (i < NODES) ? cnt[r * NODES + i] : 0;
    int x = v;
#pragma unroll
    for (int s = 1; s < 64; s <<= 1) {
      int t = __shfl_up(x, s, 64);
      if (lane >= s) x += t;
    }
    if (lane == 63) wsum[wid] = x;
    __syncthreads();
    if (threadIdx.x < 16) {
      int w = wsum[threadIdx.x];
#pragma unroll
      for (int s = 1; s < 16; s <<= 1) {
        int t = __shfl_up(w, s, 16);
        if ((threadIdx.x & 15) >= s) w += t;
      }
      wsum[threadIdx.x] = w;
    }
    __syncthreads();
    int wexcl = (wid == 0) ? 0 : wsum[wid - 1];
    if (i < NODES) rowoff[r * (NODES + 1) + i] = running + wexcl + x - v;
    int tot = wsum[15];
    __syncthreads();
    running += tot;
  }
  if (threadIdx.x == 0) rowoff[r * (NODES + 1) + NODES] = running;
}

__global__ void k_scatter(const int* __restrict__ edges, const int* __restrict__ rowoff,
                          int* __restrict__ cur, int* __restrict__ csr) {
  int idx = blockIdx.x * blockDim.x + threadIdx.x;
  if (idx >= NREL * EDGES) return;
  int r = idx / EDGES;
  int e = idx - r * EDGES;
  int src = edges[(r * 2 + 0) * EDGES + e];
  int dst = edges[(r * 2 + 1) * EDGES + e];
  int p = atomicAdd(&cur[r * NODES + dst], 1);
  csr[r * EDGES + rowoff[r * (NODES + 1) + dst] + p] = src;
}

// ---------------- prep: x -> bf16 (vectorized) ----------------
__global__ void k_xcvt(const float* __restrict__ xv, const float* __restrict__ xp,
                       unsigned short* __restrict__ xbf) {
  int idx = blockIdx.x * 256 + threadIdx.x;
  const int ND = NODES * DIN;
  int e0 = idx * 4;
  if (e0 >= 2 * ND) return;
  const float* s = (e0 < ND) ? (xv + e0) : (xp + e0 - ND);
  float4 v = *(const float4*)s;
  u16x4 o;
  o[0] = f2bf(v.x);
  o[1] = f2bf(v.y);
  o[2] = f2bf(v.z);
  o[3] = f2bf(v.w);
  *(u16x4*)(xbf + e0) = o;
}

// ---------------- prep: weight concat transpose -> bf16 ----------------
__global__ void k_wtrans(const float* __restrict__ W_l, const float* __restrict__ W_r,
                         unsigned short* __restrict__ Wt) {
  const int rels[2][3] = {{0, 1, 3}, {2, 4, 5}};
  int kt = blockIdx.x, nt = blockIdx.y, ld = blockIdx.z;
  int layer = ld >> 1, dt = ld & 1;
  __shared__ float sh[16][17];
  int k0 = kt * 16, n0 = nt * 16;
  int seg = k0 >> 8, kk0 = k0 & 255;
  int tx = threadIdx.x, ty = threadIdx.y;
  float v;
  if (seg < 3) {
    v = W_l[(((size_t)layer * NREL + rels[dt][seg]) * HID + kk0 + ty) * HID + n0 + tx];
  } else {
    v = 0.f;
    for (int j = 0; j < 3; ++j)
      v += W_r[(((size_t)layer * NREL + rels[dt][j]) * HID + kk0 + ty) * HID + n0 + tx];
  }
  sh[ty][tx] = v;
  __syncthreads();
  Wt[((size_t)ld * HID + n0 + ty) * 1024 + k0 + tx] = f2bf(sh[tx][ty]);
}

__global__ void k_wembt(const float* __restrict__ W_emb, unsigned short* __restrict__ Wet) {
  int kt = blockIdx.x, nt = blockIdx.y, t = blockIdx.z;
  __shared__ float sh[16][17];
  int k0 = kt * 16, n0 = nt * 16;
  int tx = threadIdx.x, ty = threadIdx.y;
  sh[ty][tx] = W_emb[((size_t)t * DIN + k0 + ty) * HID + n0 + tx];
  __syncthreads();
  Wet[((size_t)t * HID + n0 + ty) * DIN + k0 + tx] = f2bf(sh[tx][ty]);
}

// both layers at once: bsum[layer][dt][256]
__global__ void k_bsum(const float* __restrict__ b_l, float* __restrict__ bsum) {
  const int rels[2][3] = {{0, 1, 3}, {2, 4, 5}};
  int idx = blockIdx.x * 256 + threadIdx.x;
  if (idx >= 1024) return;
  int layer = idx >> 9, dt = (idx >> 8) & 1, c = idx & 255;
  float s = 0.f;
  for (int j = 0; j < 3; ++j) s += b_l[(layer * NREL + rels[dt][j]) * HID + c];
  bsum[idx] = s;
}

// ---------------- fused aggregation, XCD column-partitioned, VALU-lean ----------------
// grid (8, 157, 3): x = st*4 + chunk (128B col chunk), y = 128-row block, z = rel in type.
__global__ __launch_bounds__(256) void k_agg(unsigned short* __restrict__ a0,
                                             unsigned short* __restrict__ a1,
                                             const int* __restrict__ rowoff,
                                             const int* __restrict__ csr) {
  const int dt_of[6] = {0, 0, 1, 0, 1, 1};
  const int seg_of[6] = {0, 1, 0, 2, 1, 2};
  int x = blockIdx.x;
  int st = x >> 2, chunk = x & 3;
  int rel = st * 3 + blockIdx.z;
  int dt = dt_of[rel], seg = seg_of[rel];
  const char* src = (const char*)((st == 0 ? a0 : a1) + 768 + chunk * 64);
  unsigned short* dst = (dt == 0 ? a0 : a1) + seg * 256 + chunk * 64;
  int lane16 = threadIdx.x & 15;
  int rsub = threadIdx.x >> 4;
  unsigned coff = (unsigned)lane16 * 8u;  // byte offset within 128B chunk
  const int* ro = rowoff + rel * (NODES + 1);
  const int* lst = csr + (size_t)rel * EDGES;
  int rbase = blockIdx.y * 128;
#define LD(s) (*(const uint2*)(src + (((unsigned)(s) << 11) + coff)))
#define ACCV(v)                                \
  {                                            \
    aL0 += __uint_as_float((v).x << 16);       \
    aH0 += __uint_as_float((v).x & 0xffff0000u); \
    aL1 += __uint_as_float((v).y << 16);       \
    aH1 += __uint_as_float((v).y & 0xffff0000u); \
  }
#pragma unroll 1
  for (int pass = 0; pass < 8; ++pass) {
    int row = rbase + pass * 16 + rsub;
    if (row >= NODES) break;
    int o0 = ro[row], o1 = ro[row + 1];
    float aL0 = 0.f, aH0 = 0.f, aL1 = 0.f, aH1 = 0.f;
    int j = o0;
#pragma unroll 1
    for (; j + 4 <= o1; j += 4) {
      unsigned s0 = (unsigned)lst[j], s1 = (unsigned)lst[j + 1];
      unsigned s2 = (unsigned)lst[j + 2], s3 = (unsigned)lst[j + 3];
      uint2 v0 = LD(s0), v1 = LD(s1), v2 = LD(s2), v3 = LD(s3);
      ACCV(v0);
      ACCV(v1);
      ACCV(v2);
      ACCV(v3);
    }
#pragma unroll 1
    for (; j < o1; ++j) {
      uint2 v = LD((unsigned)lst[j]);
      ACCV(v);
    }
    int deg = o1 - o0;
    float inv = deg ? 1.f / (float)deg : 0.f;
    u16x4 o;
    o[0] = f2bf(aL0 * inv);
    o[1] = f2bf(aH0 * inv);
    o[2] = f2bf(aL1 * inv);
    o[3] = f2bf(aH1 * inv);
    *(u16x4*)(dst + (size_t)row * 1024 + lane16 * 4) = o;
  }
#undef LD
#undef ACCV
}

// ---------------- MFMA bf16 GEMM, double-buffered LDS ----------------
template <int K, int OUTMODE>
__global__ __launch_bounds__(256) void k_mfma(const unsigned short* __restrict__ A,
                                              const unsigned short* __restrict__ Bt,
                                              const float* __restrict__ bias,
                                              float* __restrict__ Craw,
                                              unsigned short* __restrict__ Cbf,
                                              float* __restrict__ stats) {
  __shared__ unsigned short As[2][128 * 32];
  __shared__ unsigned short Bs[2][64 * 32];
  const int bm = blockIdx.x * 128, bn = blockIdx.y * 64;
  const int tid = threadIdx.x, lane = tid & 63, w = tid >> 6;
  const int wr = w >> 1, wc = w & 1;
  const int sr = tid >> 2;
  const int soff = (tid & 3) * 16;
  const int swz = soff ^ ((sr & 6) << 3);
  int r0 = bm + sr;       if (r0 >= NODES) r0 = NODES - 1;
  int r1 = bm + 64 + sr;  if (r1 >= NODES) r1 = NODES - 1;
  const char* gA0 = (const char*)A + (size_t)r0 * K * 2 + swz;
  const char* gA1 = (const char*)A + (size_t)r1 * K * 2 + swz;
  const char* gB  = (const char*)Bt + (size_t)(bn + sr) * K * 2 + swz;

  f32x4 acc[4][2] = {};
  const int kb = (lane >> 4) * 16;

  auto stage = [&](int b, int k0) {
    GLDS(gA0 + 2 * k0, (char*)As[b] + w * 1024);
    GLDS(gA1 + 2 * k0, (char*)As[b] + 4096 + w * 1024);
    GLDS(gB + 2 * k0, (char*)Bs[b] + w * 1024);
  };

  stage(0, 0);
  __syncthreads();
  int cur = 0;
  for (int k0 = 0; k0 < K; k0 += 32) {
    if (k0 + 32 < K) stage(cur ^ 1, k0 + 32);
    const unsigned short* Ab = As[cur];
    const unsigned short* Bb = Bs[cur];
    bf16x8 bfr[2];
#pragma unroll
    for (int n = 0; n < 2; ++n) {
      int rowb = wc * 32 + n * 16 + (lane & 15);
      int off = kb ^ ((rowb & 6) << 3);
      bfr[n] = *(const bf16x8*)(Bb + rowb * 32 + (off >> 1));
    }
#pragma unroll
    for (int m = 0; m < 4; ++m) {
      int rowa = wr * 64 + m * 16 + (lane & 15);
      int off = kb ^ ((rowa & 6) << 3);
      bf16x8 afr = *(const bf16x8*)(Ab + rowa * 32 + (off >> 1));
      acc[m][0] = __builtin_amdgcn_mfma_f32_16x16x32_bf16(afr, bfr[0], acc[m][0], 0, 0, 0);
      acc[m][1] = __builtin_amdgcn_mfma_f32_16x16x32_bf16(afr, bfr[1], acc[m][1], 0, 0, 0);
    }
    __syncthreads();
    cur ^= 1;
  }

#pragma unroll
  for (int n = 0; n < 2; ++n) {
    int col = bn + wc * 32 + n * 16 + (lane & 15);
    float bv = bias[col];
    float s = 0.f, s2 = 0.f;
#pragma unroll
    for (int m = 0; m < 4; ++m) {
#pragma unroll
      for (int q = 0; q < 4; ++q) {
        int row = bm + wr * 64 + m * 16 + ((lane >> 4) * 4) + q;
        if (row < NODES) {
          float v = acc[m][n][q] + bv;
          if (OUTMODE == 0) {
            Craw[(size_t)row * 256 + col] = v;
            s += v;
            s2 = fmaf(v, v, s2);
          } else {
            Cbf[(size_t)row * 1024 + col] = f2bf(v);
          }
        }
      }
    }
    if (OUTMODE == 0) {
      s += __shfl_xor(s, 16);
      s += __shfl_xor(s, 32);
      s2 += __shfl_xor(s2, 16);
      s2 += __shfl_xor(s2, 32);
      if (lane < 16) {
        atomicAdd(&stats[col], s);
        atomicAdd(&stats[256 + col], s2);
      }
    }
  }
}

// ---------------- BN apply (layer 0): raw fp32 -> bf16 xs slice ----------------
__global__ __launch_bounds__(256) void k_bnapply(const float* __restrict__ raw,
                                                 const float* __restrict__ stats,
                                                 const float* __restrict__ gamma,
                                                 const float* __restrict__ beta,
                                                 unsigned short* __restrict__ out) {
  int idx = blockIdx.x * 256 + threadIdx.x;
  if (idx >= NODES * 256) return;
  int c = idx & 255;
  int rrow = idx >> 8;
  const float inv3 = 1.f / 3.f;
  float m = stats[c] * (inv3 / NODES);
  float ex2 = stats[256 + c] * (inv3 * inv3 / NODES);
  float var = ex2 - m * m;
  float v = (raw[idx] * inv3 - m) * rsqrtf(var + 1e-5f) * gamma[c] + beta[c];
  out[(size_t)rrow * 1024 + c] = f2bf(fmaxf(v, 0.f));
}

// ---------------- pooling (fused layer-1 BN+relu+residual) ----------------
__global__ __launch_bounds__(256) void k_pool(const float* __restrict__ raw,
                                              const float* __restrict__ stats,
                                              const float* __restrict__ gamma,
                                              const float* __restrict__ beta,
                                              const unsigned short* __restrict__ prev,
                                              const int* __restrict__ batch,
                                              float* __restrict__ pooled,
                                              float* __restrict__ gcnt) {
  int c = threadIdx.x;
  int rows_per = (NODES + gridDim.x - 1) / gridDim.x;
  int r0 = blockIdx.x * rows_per;
  int r1 = min(NODES, r0 + rows_per);
  if (r0 >= NODES) return;
  const float inv3 = 1.f / 3.f;
  float m = stats[c] * (inv3 / NODES);
  float ex2 = stats[256 + c] * (inv3 * inv3 / NODES);
  float rs = rsqrtf(ex2 - m * m + 1e-5f) * gamma[c];
  float bt = beta[c];
  float s = 0.f;
  int curg = batch[r0];
  for (int r = r0; r < r1; ++r) {
    int g = batch[r];
    if (g != curg) {
      atomicAdd(&pooled[curg * 256 + c], s);
      s = 0.f;
      curg = g;
    }
    float v = fmaxf((raw[(size_t)r * 256 + c] * inv3 - m) * rs + bt, 0.f) +
              bf2f(prev[(size_t)r * 1024 + c]);
    s += v;
  }
  atomicAdd(&pooled[curg * 256 + c], s);
  if (c == 0) {
    int cn = 0;
    int cg = batch[r0];
    for (int r = r0; r < r1; ++r) {
      int g = batch[r];
      if (g != cg) {
        atomicAdd(&gcnt[cg], (float)cn);
        cn = 0;
        cg = g;
      }
      cn++;
    }
    atomicAdd(&gcnt[cg], (float)cn);
  }
}

__global__ __launch_bounds__(256) void k_final(const float* __restrict__ pooled,
                                               const float* __restrict__ gcnt,
                                               const float* __restrict__ Wout,
                                               const float* __restrict__ bout,
                                               float* __restrict__ out) {
  int g = blockIdx.x;
  int h = threadIdx.x;
  float cv = fmaxf(gcnt[g], 1.f);
  float cp = fmaxf(gcnt[NGRAPH + g], 1.f);
  float v = pooled[g * 256 + h] / cv * Wout[h] +
            pooled[NGRAPH * 256 + g * 256 + h] / cp * Wout[256 + h];
#pragma unroll
  for (int s = 32; s > 0; s >>= 1) v += __shfl_down(v, s, 64);
  __shared__ float sh[4];
  if ((h & 63) == 0) sh[h >> 6] = v;
  __syncthreads();
  if (h == 0) {
    float t = sh[0] + sh[1] + sh[2] + sh[3] + bout[0];
    out[g] = 1.f / (1.f + expf(-t));
  }
}

// ---------------- host ----------------
extern "C" void kernel_launch(void* const* d_in, const int* in_sizes, int n_in,
                              void* d_out, int out_size, void* d_ws, size_t ws_size,
                              hipStream_t stream) {
  const float* x_vuln = (const float*)d_in[0];
  const float* x_patch = (const float*)d_in[1];
  const float* W_emb = (const float*)d_in[2];
  const float* b_emb = (const float*)d_in[3];
  const float* W_l = (const float*)d_in[4];
  const float* b_l = (const float*)d_in[5];
  const float* W_r = (const float*)d_in[6];
  const float* gamma = (const float*)d_in[7];
  const float* beta = (const float*)d_in[8];
  const float* W_out = (const float*)d_in[9];
  const float* b_out = (const float*)d_in[10];
  const int* edge_index = (const int*)d_in[11];
  const int* batch_vuln = (const int*)d_in[12];
  const int* batch_patch = (const int*)d_in[13];

  char* ws = (char*)d_ws;
  size_t off = 0;
  auto alloc = [&](size_t bytes) -> void* {
    void* p = ws + off;
    off = (off + bytes + 255) & ~(size_t)255;
    return p;
  };
  int* csr = (int*)alloc((size_t)NREL * EDGES * 4);
  int* rowoff = (int*)alloc((size_t)NREL * (NODES + 1) * 4);
  unsigned short* Acat[2];
  Acat[0] = (unsigned short*)alloc((size_t)NODES * 1024 * 2);
  Acat[1] = (unsigned short*)alloc((size_t)NODES * 1024 * 2);
  float* raw[2];
  raw[0] = (float*)alloc((size_t)NODES * 256 * 4);
  raw[1] = (float*)alloc((size_t)NODES * 256 * 4);
  unsigned short* xbf = (unsigned short*)alloc((size_t)2 * NODES * DIN * 2);
  unsigned short* Wt = (unsigned short*)alloc((size_t)4 * 256 * 1024 * 2);
  unsigned short* Wet = (unsigned short*)alloc((size_t)2 * 256 * DIN * 2);
  float* bsum = (float*)alloc(1024 * 4);  // [layer][dt][256]
  // ---- contiguous zero region ----
  size_t zoff0 = off;
  int* cnt = (int*)alloc((size_t)NREL * NODES * 4);
  int* cur = (int*)alloc((size_t)NREL * NODES * 4);
  float* stats = (float*)alloc((size_t)2 * 2 * 512 * 4);  // [layer][dt][{sum,sumsq}x256]
  float* pooled = (float*)alloc((size_t)2 * NGRAPH * 256 * 4);
  float* gcnt = (float*)alloc((size_t)2 * NGRAPH * 4);
  size_t zbytes = off - zoff0;
  hipMemsetAsync(ws + zoff0, 0, zbytes, stream);

  int tot_e = NREL * EDGES;
  k_hist<<<(tot_e + 255) / 256, 256, 0, stream>>>(edge_index, cnt);
  k_scan<<<NREL, 1024, 0, stream>>>(cnt, rowoff);
  k_scatter<<<(tot_e + 255) / 256, 256, 0, stream>>>(edge_index, rowoff, cur, csr);

  k_xcvt<<<(2 * NODES * DIN / 4 + 255) / 256, 256, 0, stream>>>(x_vuln, x_patch, xbf);
  k_wtrans<<<dim3(64, 16, 4), dim3(16, 16), 0, stream>>>(W_l, W_r, Wt);
  k_wembt<<<dim3(8, 16, 2), dim3(16, 16), 0, stream>>>(W_emb, Wet);
  k_bsum<<<4, 256, 0, stream>>>(b_l, bsum);

  dim3 ggrid(157, 4);
  for (int t = 0; t < 2; ++t)
    k_mfma<DIN, 1><<<ggrid, 256, 0, stream>>>(xbf + (size_t)t * NODES * DIN,
                                              Wet + (size_t)t * 256 * DIN,
                                              b_emb + t * 256, nullptr,
                                              Acat[t] + 768, nullptr);

  for (int layer = 0; layer < 2; ++layer) {
    k_agg<<<dim3(8, 157, 3), 256, 0, stream>>>(Acat[0], Acat[1], rowoff, csr);
    for (int dt = 0; dt < 2; ++dt)
      k_mfma<1024, 0><<<ggrid, 256, 0, stream>>>(
          Acat[dt], Wt + (size_t)(layer * 2 + dt) * 256 * 1024,
          bsum + (layer * 2 + dt) * 256, raw[dt], nullptr,
          stats + (layer * 2 + dt) * 512);
    if (layer == 0) {
      for (int dt = 0; dt < 2; ++dt)
        k_bnapply<<<(NODES * 256 + 255) / 256, 256, 0, stream>>>(
            raw[dt], stats + dt * 512, gamma + dt * 256, beta + dt * 256,
            Acat[dt] + 768);
    }
  }

  k_pool<<<128, 256, 0, stream>>>(raw[0], stats + 2 * 512, gamma + 2 * 256,
                                  beta + 2 * 256, Acat[0] + 768, batch_vuln, pooled,
                                  gcnt);
  k_pool<<<128, 256, 0, stream>>>(raw[1], stats + 3 * 512, gamma + 3 * 256,
                                  beta + 3 * 256, Acat[1] + 768, batch_patch,
                                  pooled + NGRAPH * 256, gcnt + NGRAPH);
  k_final<<<NGRAPH, 256, 0, stream>>>(pooled, gcnt, W_out, b_out, (float*)d_out);
}

// Round 5
// 740.016 us; speedup vs baseline: 2.8129x; 1.0083x over previous
//
#include <hip/hip_runtime.h>
#include <math.h>

#define NODES 20000
#define EDGES 320000
#define DIN 128
#define HID 256
#define NGRAPH 32
#define NREL 6

typedef __attribute__((ext_vector_type(8))) short bf16x8;
typedef __attribute__((ext_vector_type(8))) unsigned short u16x8;
typedef __attribute__((ext_vector_type(4))) unsigned short u16x4;
typedef __attribute__((ext_vector_type(4))) float f32x4;

__device__ __forceinline__ float bf2f(unsigned short u) {
  return __uint_as_float(((unsigned)u) << 16);
}
__device__ __forceinline__ unsigned short f2bf(float f) {
  unsigned u = __float_as_uint(f);
  unsigned r = (u + 0x7fffu + ((u >> 16) & 1u)) >> 16;
  return (unsigned short)r;
}

#define GLDS(g, l)                                                            \
  __builtin_amdgcn_global_load_lds(                                           \
      (const __attribute__((address_space(1))) void*)(g),                     \
      (__attribute__((address_space(3))) void*)(l), 16, 0, 0)

// ---------------- CSR build ----------------
__global__ void k_hist(const int* __restrict__ edges, int* __restrict__ cnt) {
  int idx = blockIdx.x * blockDim.x + threadIdx.x;
  if (idx >= NREL * EDGES) return;
  int r = idx / EDGES;
  int e = idx - r * EDGES;
  int dst = edges[(r * 2 + 1) * EDGES + e];
  atomicAdd(&cnt[r * NODES + dst], 1);
}

__global__ __launch_bounds__(1024) void k_scan(const int* __restrict__ cnt,
                                               int* __restrict__ rowoff) {
  int r = blockIdx.x;
  __shared__ int wsum[16];
  int lane = threadIdx.x & 63, wid = threadIdx.x >> 6;
  int running = 0;
  for (int base = 0; base < NODES; base += 1024) {
    int i = base + threadIdx.x;
    int v = (i < NODES) ? cnt[r * NODES + i] : 0;
    int x = v;
#pragma unroll
    for (int s = 1; s < 64; s <<= 1) {
      int t = __shfl_up(x, s, 64);
      if (lane >= s) x += t;
    }
    if (lane == 63) wsum[wid] = x;
    __syncthreads();
    if (threadIdx.x < 16) {
      int w = wsum[threadIdx.x];
#pragma unroll
      for (int s = 1; s < 16; s <<= 1) {
        int t = __shfl_up(w, s, 16);
        if ((threadIdx.x & 15) >= s) w += t;
      }
      wsum[threadIdx.x] = w;
    }
    __syncthreads();
    int wexcl = (wid == 0) ? 0 : wsum[wid - 1];
    if (i < NODES) rowoff[r * (NODES + 1) + i] = running + wexcl + x - v;
    int tot = wsum[15];
    __syncthreads();
    running += tot;
  }
  if (threadIdx.x == 0) rowoff[r * (NODES + 1) + NODES] = running;
}

__global__ void k_scatter(const int* __restrict__ edges, const int* __restrict__ rowoff,
                          int* __restrict__ cur, int* __restrict__ csr) {
  int idx = blockIdx.x * blockDim.x + threadIdx.x;
  if (idx >= NREL * EDGES) return;
  int r = idx / EDGES;
  int e = idx - r * EDGES;
  int src = edges[(r * 2 + 0) * EDGES + e];
  int dst = edges[(r * 2 + 1) * EDGES + e];
  int p = atomicAdd(&cur[r * NODES + dst], 1);
  csr[r * EDGES + rowoff[r * (NODES + 1) + dst] + p] = src;
}

// ---------------- prep: x -> bf16 (vectorized) ----------------
__global__ void k_xcvt(const float* __restrict__ xv, const float* __restrict__ xp,
                       unsigned short* __restrict__ xbf) {
  int idx = blockIdx.x * 256 + threadIdx.x;
  const int ND = NODES * DIN;
  int e0 = idx * 4;
  if (e0 >= 2 * ND) return;
  const float* s = (e0 < ND) ? (xv + e0) : (xp + e0 - ND);
  float4 v = *(const float4*)s;
  u16x4 o;
  o[0] = f2bf(v.x);
  o[1] = f2bf(v.y);
  o[2] = f2bf(v.z);
  o[3] = f2bf(v.w);
  *(u16x4*)(xbf + e0) = o;
}

// ---------------- prep: weight concat transpose -> bf16 ----------------
__global__ void k_wtrans(const float* __restrict__ W_l, const float* __restrict__ W_r,
                         unsigned short* __restrict__ Wt) {
  const int rels[2][3] = {{0, 1, 3}, {2, 4, 5}};
  int kt = blockIdx.x, nt = blockIdx.y, ld = blockIdx.z;
  int layer = ld >> 1, dt = ld & 1;
  __shared__ float sh[16][17];
  int k0 = kt * 16, n0 = nt * 16;
  int seg = k0 >> 8, kk0 = k0 & 255;
  int tx = threadIdx.x, ty = threadIdx.y;
  float v;
  if (seg < 3) {
    v = W_l[(((size_t)layer * NREL + rels[dt][seg]) * HID + kk0 + ty) * HID + n0 + tx];
  } else {
    v = 0.f;
    for (int j = 0; j < 3; ++j)
      v += W_r[(((size_t)layer * NREL + rels[dt][j]) * HID + kk0 + ty) * HID + n0 + tx];
  }
  sh[ty][tx] = v;
  __syncthreads();
  Wt[((size_t)ld * HID + n0 + ty) * 1024 + k0 + tx] = f2bf(sh[tx][ty]);
}

__global__ void k_wembt(const float* __restrict__ W_emb, unsigned short* __restrict__ Wet) {
  int kt = blockIdx.x, nt = blockIdx.y, t = blockIdx.z;
  __shared__ float sh[16][17];
  int k0 = kt * 16, n0 = nt * 16;
  int tx = threadIdx.x, ty = threadIdx.y;
  sh[ty][tx] = W_emb[((size_t)t * DIN + k0 + ty) * HID + n0 + tx];
  __syncthreads();
  Wet[((size_t)t * HID + n0 + ty) * DIN + k0 + tx] = f2bf(sh[tx][ty]);
}

// both layers at once: bsum[layer][dt][256]
__global__ void k_bsum(const float* __restrict__ b_l, float* __restrict__ bsum) {
  const int rels[2][3] = {{0, 1, 3}, {2, 4, 5}};
  int idx = blockIdx.x * 256 + threadIdx.x;
  if (idx >= 1024) return;
  int layer = idx >> 9, dt = (idx >> 8) & 1, c = idx & 255;
  float s = 0.f;
  for (int j = 0; j < 3; ++j) s += b_l[(layer * NREL + rels[dt][j]) * HID + c];
  bsum[idx] = s;
}

// ---------------- fused aggregation, XCD column-partitioned, pipelined ----------------
// grid (8, 157, 3): x = st*4 + chunk (128B col chunk), y = 128-row block, z = rel in type.
__global__ __launch_bounds__(256) void k_agg(unsigned short* __restrict__ a0,
                                             unsigned short* __restrict__ a1,
                                             const int* __restrict__ rowoff,
                                             const int* __restrict__ csr) {
  const int dt_of[6] = {0, 0, 1, 0, 1, 1};
  const int seg_of[6] = {0, 1, 0, 2, 1, 2};
  int x = blockIdx.x;
  int st = x >> 2, chunk = x & 3;
  int rel = st * 3 + blockIdx.z;
  int dt = dt_of[rel], seg = seg_of[rel];
  const char* src = (const char*)((st == 0 ? a0 : a1) + 768 + chunk * 64);
  unsigned short* dst = (dt == 0 ? a0 : a1) + seg * 256 + chunk * 64;
  int lane16 = threadIdx.x & 15;
  int rsub = threadIdx.x >> 4;
  unsigned coff = (unsigned)lane16 * 8u;
  const int* ro = rowoff + rel * (NODES + 1);
  const int* lst = csr + (size_t)rel * EDGES;
  int rbase = blockIdx.y * 128;
#define LD(s) (*(const uint2*)(src + (((unsigned)(s) << 11) + coff)))
#define ACCV(v)                                  \
  {                                              \
    aL0 += __uint_as_float((v).x << 16);         \
    aH0 += __uint_as_float((v).x & 0xffff0000u); \
    aL1 += __uint_as_float((v).y << 16);         \
    aH1 += __uint_as_float((v).y & 0xffff0000u); \
  }
  int row = rbase + rsub;
  int o0 = 0, o1 = 0;
  if (row < NODES) {
    o0 = ro[row];
    o1 = ro[row + 1];
  }
#pragma unroll 1
  for (int pass = 0; pass < 8; ++pass) {
    int nrow = row + 16;
    int p0 = 0, p1 = 0;
    if (pass < 7 && nrow < NODES) {  // prefetch next pass's offsets
      p0 = ro[nrow];
      p1 = ro[nrow + 1];
    }
    if (row < NODES) {
      float aL0 = 0.f, aH0 = 0.f, aL1 = 0.f, aH1 = 0.f;
      int nb = o1 - o0;
      int nfull = nb >> 3;
      int j = o0;
      if (nfull > 0) {
        unsigned idx[8];
#pragma unroll
        for (int b = 0; b < 8; ++b) idx[b] = (unsigned)lst[j + b];
#pragma unroll 1
        for (int f = 1;; ++f) {
          uint2 v[8];
#pragma unroll
          for (int b = 0; b < 8; ++b) v[b] = LD(idx[b]);
          j += 8;
          bool more = (f < nfull);
          if (more) {
#pragma unroll
            for (int b = 0; b < 8; ++b) idx[b] = (unsigned)lst[j + b];
          }
#pragma unroll
          for (int b = 0; b < 8; ++b) ACCV(v[b]);
          if (!more) break;
        }
      }
      int rem = nb & 7;
      if (rem & 4) {
        unsigned i0 = lst[j], i1 = lst[j + 1], i2 = lst[j + 2], i3 = lst[j + 3];
        uint2 v0 = LD(i0), v1 = LD(i1), v2 = LD(i2), v3 = LD(i3);
        ACCV(v0);
        ACCV(v1);
        ACCV(v2);
        ACCV(v3);
        j += 4;
      }
      if (rem & 2) {
        unsigned i0 = lst[j], i1 = lst[j + 1];
        uint2 v0 = LD(i0), v1 = LD(i1);
        ACCV(v0);
        ACCV(v1);
        j += 2;
      }
      if (rem & 1) {
        uint2 v0 = LD((unsigned)lst[j]);
        ACCV(v0);
      }
      float inv = nb ? 1.f / (float)nb : 0.f;
      u16x4 o;
      o[0] = f2bf(aL0 * inv);
      o[1] = f2bf(aH0 * inv);
      o[2] = f2bf(aL1 * inv);
      o[3] = f2bf(aH1 * inv);
      *(u16x4*)(dst + (size_t)row * 1024 + lane16 * 4) = o;
    }
    row = nrow;
    o0 = p0;
    o1 = p1;
  }
#undef LD
#undef ACCV
}

// ---------------- MFMA bf16 GEMM, BM=128 BN=64 BK=64, double-buffered LDS ----------------
// LDS rows of 128B, 8x16B chunks, XOR-swizzled: chunk' = chunk ^ (row&7).
template <int K, int OUTMODE>
__global__ __launch_bounds__(256) void k_mfma(const unsigned short* __restrict__ A,
                                              const unsigned short* __restrict__ Bt,
                                              const float* __restrict__ bias,
                                              float* __restrict__ Craw,
                                              unsigned short* __restrict__ Cbf,
                                              float* __restrict__ stats) {
  __shared__ unsigned short As[2][128 * 64];
  __shared__ unsigned short Bs[2][64 * 64];
  const int bm = blockIdx.x * 128, bn = blockIdx.y * 64;
  const int tid = threadIdx.x, lane = tid & 63, w = tid >> 6;
  const int wr = w >> 1, wc = w & 1;
  // staging: per GLDS call, wave w writes 1KB = 8 rows x 128B (lane l: row +l>>3, chunk l&7)
  const int srow = lane >> 3;
  const int schunk = lane & 7;
  const unsigned char* gA[4];
  const unsigned char* gB[2];
#pragma unroll
  for (int c = 0; c < 4; ++c) {
    int lr = 32 * c + w * 8 + srow;
    int r = bm + lr;
    if (r >= NODES) r = NODES - 1;
    gA[c] = (const unsigned char*)A + (size_t)r * K * 2 + ((schunk ^ (lr & 7)) * 16);
  }
#pragma unroll
  for (int c = 0; c < 2; ++c) {
    int lr = 32 * c + w * 8 + srow;
    gB[c] = (const unsigned char*)Bt + (size_t)(bn + lr) * K * 2 + ((schunk ^ (lr & 7)) * 16);
  }

  auto stage = [&](int b, int k0) {
#pragma unroll
    for (int c = 0; c < 4; ++c) GLDS(gA[c] + 2 * k0, (char*)As[b] + c * 4096 + w * 1024);
#pragma unroll
    for (int c = 0; c < 2; ++c) GLDS(gB[c] + 2 * k0, (char*)Bs[b] + c * 4096 + w * 1024);
  };

  f32x4 acc[4][2] = {};
  stage(0, 0);
  __syncthreads();
  int cur = 0;
  for (int k0 = 0; k0 < K; k0 += 64) {
    if (k0 + 64 < K) stage(cur ^ 1, k0 + 64);
    const unsigned short* Ab = As[cur];
    const unsigned short* Bb = Bs[cur];
#pragma unroll
    for (int ks = 0; ks < 2; ++ks) {
      const int ci = ks * 4 + (lane >> 4);
      bf16x8 bfr[2];
#pragma unroll
      for (int n = 0; n < 2; ++n) {
        int rb = wc * 32 + n * 16 + (lane & 15);
        bfr[n] = *(const bf16x8*)((const char*)Bb + rb * 128 + ((ci ^ (rb & 7)) * 16));
      }
#pragma unroll
      for (int m = 0; m < 4; ++m) {
        int ra = wr * 64 + m * 16 + (lane & 15);
        bf16x8 afr = *(const bf16x8*)((const char*)Ab + ra * 128 + ((ci ^ (ra & 7)) * 16));
        acc[m][0] =
            __builtin_amdgcn_mfma_f32_16x16x32_bf16(afr, bfr[0], acc[m][0], 0, 0, 0);
        acc[m][1] =
            __builtin_amdgcn_mfma_f32_16x16x32_bf16(afr, bfr[1], acc[m][1], 0, 0, 0);
      }
    }
    __syncthreads();
    cur ^= 1;
  }

#pragma unroll
  for (int n = 0; n < 2; ++n) {
    int col = bn + wc * 32 + n * 16 + (lane & 15);
    float bv = bias[col];
    float s = 0.f, s2 = 0.f;
#pragma unroll
    for (int m = 0; m < 4; ++m) {
#pragma unroll
      for (int q = 0; q < 4; ++q) {
        int row = bm + wr * 64 + m * 16 + ((lane >> 4) * 4) + q;
        if (row < NODES) {
          float v = acc[m][n][q] + bv;
          if (OUTMODE == 0) {
            Craw[(size_t)row * 256 + col] = v;
            s += v;
            s2 = fmaf(v, v, s2);
          } else {
            Cbf[(size_t)row * 1024 + col] = f2bf(v);
          }
        }
      }
    }
    if (OUTMODE == 0) {
      s += __shfl_xor(s, 16);
      s += __shfl_xor(s, 32);
      s2 += __shfl_xor(s2, 16);
      s2 += __shfl_xor(s2, 32);
      if (lane < 16) {
        atomicAdd(&stats[col], s);
        atomicAdd(&stats[256 + col], s2);
      }
    }
  }
}

// ---------------- BN apply (layer 0): raw fp32 -> bf16 xs slice ----------------
__global__ __launch_bounds__(256) void k_bnapply(const float* __restrict__ raw,
                                                 const float* __restrict__ stats,
                                                 const float* __restrict__ gamma,
                                                 const float* __restrict__ beta,
                                                 unsigned short* __restrict__ out) {
  int idx = blockIdx.x * 256 + threadIdx.x;
  if (idx >= NODES * 256) return;
  int c = idx & 255;
  int rrow = idx >> 8;
  const float inv3 = 1.f / 3.f;
  float m = stats[c] * (inv3 / NODES);
  float ex2 = stats[256 + c] * (inv3 * inv3 / NODES);
  float var = ex2 - m * m;
  float v = (raw[idx] * inv3 - m) * rsqrtf(var + 1e-5f) * gamma[c] + beta[c];
  out[(size_t)rrow * 1024 + c] = f2bf(fmaxf(v, 0.f));
}

// ---------------- pooling (fused layer-1 BN+relu+residual) ----------------
__global__ __launch_bounds__(256) void k_pool(const float* __restrict__ raw,
                                              const float* __restrict__ stats,
                                              const float* __restrict__ gamma,
                                              const float* __restrict__ beta,
                                              const unsigned short* __restrict__ prev,
                                              const int* __restrict__ batch,
                                              float* __restrict__ pooled,
                                              float* __restrict__ gcnt) {
  int c = threadIdx.x;
  int rows_per = (NODES + gridDim.x - 1) / gridDim.x;
  int r0 = blockIdx.x * rows_per;
  int r1 = min(NODES, r0 + rows_per);
  if (r0 >= NODES) return;
  const float inv3 = 1.f / 3.f;
  float m = stats[c] * (inv3 / NODES);
  float ex2 = stats[256 + c] * (inv3 * inv3 / NODES);
  float rs = rsqrtf(ex2 - m * m + 1e-5f) * gamma[c];
  float bt = beta[c];
  float s = 0.f;
  int curg = batch[r0];
  for (int r = r0; r < r1; ++r) {
    int g = batch[r];
    if (g != curg) {
      atomicAdd(&pooled[curg * 256 + c], s);
      s = 0.f;
      curg = g;
    }
    float v = fmaxf((raw[(size_t)r * 256 + c] * inv3 - m) * rs + bt, 0.f) +
              bf2f(prev[(size_t)r * 1024 + c]);
    s += v;
  }
  atomicAdd(&pooled[curg * 256 + c], s);
  if (c == 0) {
    int cn = 0;
    int cg = batch[r0];
    for (int r = r0; r < r1; ++r) {
      int g = batch[r];
      if (g != cg) {
        atomicAdd(&gcnt[cg], (float)cn);
        cn = 0;
        cg = g;
      }
      cn++;
    }
    atomicAdd(&gcnt[cg], (float)cn);
  }
}

__global__ __launch_bounds__(256) void k_final(const float* __restrict__ pooled,
                                               const float* __restrict__ gcnt,
                                               const float* __restrict__ Wout,
                                               const float* __restrict__ bout,
                                               float* __restrict__ out) {
  int g = blockIdx.x;
  int h = threadIdx.x;
  float cv = fmaxf(gcnt[g], 1.f);
  float cp = fmaxf(gcnt[NGRAPH + g], 1.f);
  float v = pooled[g * 256 + h] / cv * Wout[h] +
            pooled[NGRAPH * 256 + g * 256 + h] / cp * Wout[256 + h];
#pragma unroll
  for (int s = 32; s > 0; s >>= 1) v += __shfl_down(v, s, 64);
  __shared__ float sh[4];
  if ((h & 63) == 0) sh[h >> 6] = v;
  __syncthreads();
  if (h == 0) {
    float t = sh[0] + sh[1] + sh[2] + sh[3] + bout[0];
    out[g] = 1.f / (1.f + expf(-t));
  }
}

// ---------------- host ----------------
extern "C" void kernel_launch(void* const* d_in, const int* in_sizes, int n_in,
                              void* d_out, int out_size, void* d_ws, size_t ws_size,
                              hipStream_t stream) {
  const float* x_vuln = (const float*)d_in[0];
  const float* x_patch = (const float*)d_in[1];
  const float* W_emb = (const float*)d_in[2];
  const float* b_emb = (const float*)d_in[3];
  const float* W_l = (const float*)d_in[4];
  const float* b_l = (const float*)d_in[5];
  const float* W_r = (const float*)d_in[6];
  const float* gamma = (const float*)d_in[7];
  const float* beta = (const float*)d_in[8];
  const float* W_out = (const float*)d_in[9];
  const float* b_out = (const float*)d_in[10];
  const int* edge_index = (const int*)d_in[11];
  const int* batch_vuln = (const int*)d_in[12];
  const int* batch_patch = (const int*)d_in[13];

  char* ws = (char*)d_ws;
  size_t off = 0;
  auto alloc = [&](size_t bytes) -> void* {
    void* p = ws + off;
    off = (off + bytes + 255) & ~(size_t)255;
    return p;
  };
  int* csr = (int*)alloc((size_t)NREL * EDGES * 4);
  int* rowoff = (int*)alloc((size_t)NREL * (NODES + 1) * 4);
  unsigned short* Acat[2];
  Acat[0] = (unsigned short*)alloc((size_t)NODES * 1024 * 2);
  Acat[1] = (unsigned short*)alloc((size_t)NODES * 1024 * 2);
  float* raw[2];
  raw[0] = (float*)alloc((size_t)NODES * 256 * 4);
  raw[1] = (float*)alloc((size_t)NODES * 256 * 4);
  unsigned short* xbf = (unsigned short*)alloc((size_t)2 * NODES * DIN * 2);
  unsigned short* Wt = (unsigned short*)alloc((size_t)4 * 256 * 1024 * 2);
  unsigned short* Wet = (unsigned short*)alloc((size_t)2 * 256 * DIN * 2);
  float* bsum = (float*)alloc(1024 * 4);  // [layer][dt][256]
  // ---- contiguous zero region ----
  size_t zoff0 = off;
  int* cnt = (int*)alloc((size_t)NREL * NODES * 4);
  int* cur = (int*)alloc((size_t)NREL * NODES * 4);
  float* stats = (float*)alloc((size_t)2 * 2 * 512 * 4);  // [layer][dt][{sum,sumsq}x256]
  float* pooled = (float*)alloc((size_t)2 * NGRAPH * 256 * 4);
  float* gcnt = (float*)alloc((size_t)2 * NGRAPH * 4);
  size_t zbytes = off - zoff0;
  hipMemsetAsync(ws + zoff0, 0, zbytes, stream);

  int tot_e = NREL * EDGES;
  k_hist<<<(tot_e + 255) / 256, 256, 0, stream>>>(edge_index, cnt);
  k_scan<<<NREL, 1024, 0, stream>>>(cnt, rowoff);
  k_scatter<<<(tot_e + 255) / 256, 256, 0, stream>>>(edge_index, rowoff, cur, csr);

  k_xcvt<<<(2 * NODES * DIN / 4 + 255) / 256, 256, 0, stream>>>(x_vuln, x_patch, xbf);
  k_wtrans<<<dim3(64, 16, 4), dim3(16, 16), 0, stream>>>(W_l, W_r, Wt);
  k_wembt<<<dim3(8, 16, 2), dim3(16, 16), 0, stream>>>(W_emb, Wet);
  k_bsum<<<4, 256, 0, stream>>>(b_l, bsum);

  dim3 ggrid(157, 4);
  for (int t = 0; t < 2; ++t)
    k_mfma<DIN, 1><<<ggrid, 256, 0, stream>>>(xbf + (size_t)t * NODES * DIN,
                                              Wet + (size_t)t * 256 * DIN,
                                              b_emb + t * 256, nullptr,
                                              Acat[t] + 768, nullptr);

  for (int layer = 0; layer < 2; ++layer) {
    k_agg<<<dim3(8, 157, 3), 256, 0, stream>>>(Acat[0], Acat[1], rowoff, csr);
    for (int dt = 0; dt < 2; ++dt)
      k_mfma<1024, 0><<<ggrid, 256, 0, stream>>>(
          Acat[dt], Wt + (size_t)(layer * 2 + dt) * 256 * 1024,
          bsum + (layer * 2 + dt) * 256, raw[dt], nullptr,
          stats + (layer * 2 + dt) * 512);
    if (layer == 0) {
      for (int dt = 0; dt < 2; ++dt)
        k_bnapply<<<(NODES * 256 + 255) / 256, 256, 0, stream>>>(
            raw[dt], stats + dt * 512, gamma + dt * 256, beta + dt * 256,
            Acat[dt] + 768);
    }
  }

  k_pool<<<128, 256, 0, stream>>>(raw[0], stats + 2 * 512, gamma + 2 * 256,
                                  beta + 2 * 256, Acat[0] + 768, batch_vuln, pooled,
                                  gcnt);
  k_pool<<<128, 256, 0, stream>>>(raw[1], stats + 3 * 512, gamma + 3 * 256,
                                  beta + 3 * 256, Acat[1] + 768, batch_patch,
                                  pooled + NGRAPH * 256, gcnt + NGRAPH);
  k_final<<<NGRAPH, 256, 0, stream>>>(pooled, gcnt, W_out, b_out, (float*)d_out);
}

// Round 6
// 712.050 us; speedup vs baseline: 2.9234x; 1.0393x over previous
//
#include <hip/hip_runtime.h>
#include <math.h>

#define NODES 20000
#define EDGES 320000
#define DIN 128
#define HID 256
#define NGRAPH 32
#define NREL 6
#define STR 1088  // Acat row stride in shorts (2176B = 17*128B, breaks pow2 channel aliasing)

typedef __attribute__((ext_vector_type(8))) short bf16x8;
typedef __attribute__((ext_vector_type(8))) unsigned short u16x8;
typedef __attribute__((ext_vector_type(4))) unsigned short u16x4;
typedef __attribute__((ext_vector_type(4))) float f32x4;

__device__ __forceinline__ float bf2f(unsigned short u) {
  return __uint_as_float(((unsigned)u) << 16);
}
__device__ __forceinline__ unsigned short f2bf(float f) {
  unsigned u = __float_as_uint(f);
  unsigned r = (u + 0x7fffu + ((u >> 16) & 1u)) >> 16;
  return (unsigned short)r;
}

#define GLDS(g, l)                                                            \
  __builtin_amdgcn_global_load_lds(                                           \
      (const __attribute__((address_space(1))) void*)(g),                     \
      (__attribute__((address_space(3))) void*)(l), 16, 0, 0)

// ---------------- CSR build ----------------
__global__ void k_hist(const int* __restrict__ edges, int* __restrict__ cnt) {
  int idx = blockIdx.x * blockDim.x + threadIdx.x;
  if (idx >= NREL * EDGES) return;
  int r = idx / EDGES;
  int e = idx - r * EDGES;
  int dst = edges[(r * 2 + 1) * EDGES + e];
  atomicAdd(&cnt[r * NODES + dst], 1);
}

__global__ __launch_bounds__(1024) void k_scan(const int* __restrict__ cnt,
                                               int* __restrict__ rowoff) {
  int r = blockIdx.x;
  __shared__ int wsum[16];
  int lane = threadIdx.x & 63, wid = threadIdx.x >> 6;
  int running = 0;
  for (int base = 0; base < NODES; base += 1024) {
    int i = base + threadIdx.x;
    int v = (i < NODES) ? cnt[r * NODES + i] : 0;
    int x = v;
#pragma unroll
    for (int s = 1; s < 64; s <<= 1) {
      int t = __shfl_up(x, s, 64);
      if (lane >= s) x += t;
    }
    if (lane == 63) wsum[wid] = x;
    __syncthreads();
    if (threadIdx.x < 16) {
      int w = wsum[threadIdx.x];
#pragma unroll
      for (int s = 1; s < 16; s <<= 1) {
        int t = __shfl_up(w, s, 16);
        if ((threadIdx.x & 15) >= s) w += t;
      }
      wsum[threadIdx.x] = w;
    }
    __syncthreads();
    int wexcl = (wid == 0) ? 0 : wsum[wid - 1];
    if (i < NODES) rowoff[r * (NODES + 1) + i] = running + wexcl + x - v;
    int tot = wsum[15];
    __syncthreads();
    running += tot;
  }
  if (threadIdx.x == 0) rowoff[r * (NODES + 1) + NODES] = running;
}

__global__ void k_scatter(const int* __restrict__ edges, const int* __restrict__ rowoff,
                          int* __restrict__ cur, int* __restrict__ csr) {
  int idx = blockIdx.x * blockDim.x + threadIdx.x;
  if (idx >= NREL * EDGES) return;
  int r = idx / EDGES;
  int e = idx - r * EDGES;
  int src = edges[(r * 2 + 0) * EDGES + e];
  int dst = edges[(r * 2 + 1) * EDGES + e];
  int p = atomicAdd(&cur[r * NODES + dst], 1);
  csr[r * EDGES + rowoff[r * (NODES + 1) + dst] + p] = src;
}

// ---------------- prep: x -> bf16 (vectorized) ----------------
__global__ void k_xcvt(const float* __restrict__ xv, const float* __restrict__ xp,
                       unsigned short* __restrict__ xbf) {
  int idx = blockIdx.x * 256 + threadIdx.x;
  const int ND = NODES * DIN;
  int e0 = idx * 4;
  if (e0 >= 2 * ND) return;
  const float* s = (e0 < ND) ? (xv + e0) : (xp + e0 - ND);
  float4 v = *(const float4*)s;
  u16x4 o;
  o[0] = f2bf(v.x);
  o[1] = f2bf(v.y);
  o[2] = f2bf(v.z);
  o[3] = f2bf(v.w);
  *(u16x4*)(xbf + e0) = o;
}

// ---------------- prep: weight concat transpose -> bf16 ----------------
__global__ void k_wtrans(const float* __restrict__ W_l, const float* __restrict__ W_r,
                         unsigned short* __restrict__ Wt) {
  const int rels[2][3] = {{0, 1, 3}, {2, 4, 5}};
  int kt = blockIdx.x, nt = blockIdx.y, ld = blockIdx.z;
  int layer = ld >> 1, dt = ld & 1;
  __shared__ float sh[16][17];
  int k0 = kt * 16, n0 = nt * 16;
  int seg = k0 >> 8, kk0 = k0 & 255;
  int tx = threadIdx.x, ty = threadIdx.y;
  float v;
  if (seg < 3) {
    v = W_l[(((size_t)layer * NREL + rels[dt][seg]) * HID + kk0 + ty) * HID + n0 + tx];
  } else {
    v = 0.f;
    for (int j = 0; j < 3; ++j)
      v += W_r[(((size_t)layer * NREL + rels[dt][j]) * HID + kk0 + ty) * HID + n0 + tx];
  }
  sh[ty][tx] = v;
  __syncthreads();
  Wt[((size_t)ld * HID + n0 + ty) * 1024 + k0 + tx] = f2bf(sh[tx][ty]);
}

__global__ void k_wembt(const float* __restrict__ W_emb, unsigned short* __restrict__ Wet) {
  int kt = blockIdx.x, nt = blockIdx.y, t = blockIdx.z;
  __shared__ float sh[16][17];
  int k0 = kt * 16, n0 = nt * 16;
  int tx = threadIdx.x, ty = threadIdx.y;
  sh[ty][tx] = W_emb[((size_t)t * DIN + k0 + ty) * HID + n0 + tx];
  __syncthreads();
  Wet[((size_t)t * HID + n0 + ty) * DIN + k0 + tx] = f2bf(sh[tx][ty]);
}

// both layers at once: bsum[layer][dt][256]
__global__ void k_bsum(const float* __restrict__ b_l, float* __restrict__ bsum) {
  const int rels[2][3] = {{0, 1, 3}, {2, 4, 5}};
  int idx = blockIdx.x * 256 + threadIdx.x;
  if (idx >= 1024) return;
  int layer = idx >> 9, dt = (idx >> 8) & 1, c = idx & 255;
  float s = 0.f;
  for (int j = 0; j < 3; ++j) s += b_l[(layer * NREL + rels[dt][j]) * HID + c];
  bsum[idx] = s;
}

// ---------------- fused aggregation, XCD column-partitioned ----------------
// grid (8, 157, 3): x = st*4 + chunk (128B col chunk), y = 128-row block, z = rel in type.
__global__ __launch_bounds__(256) void k_agg(unsigned short* __restrict__ a0,
                                             unsigned short* __restrict__ a1,
                                             const int* __restrict__ rowoff,
                                             const int* __restrict__ csr) {
  const int dt_of[6] = {0, 0, 1, 0, 1, 1};
  const int seg_of[6] = {0, 1, 0, 2, 1, 2};
  int x = blockIdx.x;
  int st = x >> 2, chunk = x & 3;
  int rel = st * 3 + blockIdx.z;
  int dt = dt_of[rel], seg = seg_of[rel];
  const char* src = (const char*)((st == 0 ? a0 : a1) + 768 + chunk * 64);
  unsigned short* dst = (dt == 0 ? a0 : a1) + seg * 256 + chunk * 64;
  int lane16 = threadIdx.x & 15;
  int rsub = threadIdx.x >> 4;
  unsigned coff = (unsigned)lane16 * 8u;
  const int* ro = rowoff + rel * (NODES + 1);
  const int* lst = csr + (size_t)rel * EDGES;
  int rbase = blockIdx.y * 128;
#define LD(s) (*(const uint2*)(src + ((unsigned)(s) * 2176u + coff)))
#define ACCV(v)                                  \
  {                                              \
    aL0 += __uint_as_float((v).x << 16);         \
    aH0 += __uint_as_float((v).x & 0xffff0000u); \
    aL1 += __uint_as_float((v).y << 16);         \
    aH1 += __uint_as_float((v).y & 0xffff0000u); \
  }
  int row = rbase + rsub;
  int o0 = 0, o1 = 0;
  if (row < NODES) {
    o0 = ro[row];
    o1 = ro[row + 1];
  }
#pragma unroll 1
  for (int pass = 0; pass < 8; ++pass) {
    int nrow = row + 16;
    int p0 = 0, p1 = 0;
    if (pass < 7 && nrow < NODES) {
      p0 = ro[nrow];
      p1 = ro[nrow + 1];
    }
    if (row < NODES) {
      float aL0 = 0.f, aH0 = 0.f, aL1 = 0.f, aH1 = 0.f;
      int nb = o1 - o0;
      int nfull = nb >> 3;
      int j = o0;
      if (nfull > 0) {
        unsigned idx[8];
#pragma unroll
        for (int b = 0; b < 8; ++b) idx[b] = (unsigned)lst[j + b];
#pragma unroll 1
        for (int f = 1;; ++f) {
          uint2 v[8];
#pragma unroll
          for (int b = 0; b < 8; ++b) v[b] = LD(idx[b]);
          j += 8;
          bool more = (f < nfull);
          if (more) {
#pragma unroll
            for (int b = 0; b < 8; ++b) idx[b] = (unsigned)lst[j + b];
          }
#pragma unroll
          for (int b = 0; b < 8; ++b) ACCV(v[b]);
          if (!more) break;
        }
      }
      int rem = nb & 7;
      if (rem & 4) {
        unsigned i0 = lst[j], i1 = lst[j + 1], i2 = lst[j + 2], i3 = lst[j + 3];
        uint2 v0 = LD(i0), v1 = LD(i1), v2 = LD(i2), v3 = LD(i3);
        ACCV(v0);
        ACCV(v1);
        ACCV(v2);
        ACCV(v3);
        j += 4;
      }
      if (rem & 2) {
        unsigned i0 = lst[j], i1 = lst[j + 1];
        uint2 v0 = LD(i0), v1 = LD(i1);
        ACCV(v0);
        ACCV(v1);
        j += 2;
      }
      if (rem & 1) {
        uint2 v0 = LD((unsigned)lst[j]);
        ACCV(v0);
      }
      float inv = nb ? 1.f / (float)nb : 0.f;
      u16x4 o;
      o[0] = f2bf(aL0 * inv);
      o[1] = f2bf(aH0 * inv);
      o[2] = f2bf(aL1 * inv);
      o[3] = f2bf(aH1 * inv);
      *(u16x4*)(dst + (size_t)row * STR + lane16 * 4) = o;
    }
    row = nrow;
    o0 = p0;
    o1 = p1;
  }
#undef LD
#undef ACCV
}

// ---------------- MFMA bf16 GEMM, BM=128 BN=64 BK=64, dbuf LDS, XCD-swizzled grid ----
// 1D grid of 640: xcd = bid&7; all 4 bn-siblings of a bm on the same XCD (A-panel L2 reuse).
// AS = A row stride in shorts. LDS rows 128B, 8x16B chunks XOR-swizzled chunk^=(row&7).
template <int K, int AS, int OUTMODE>
__global__ __launch_bounds__(256) void k_mfma(const unsigned short* __restrict__ A,
                                              const unsigned short* __restrict__ Bt,
                                              const float* __restrict__ bias,
                                              float* __restrict__ Craw,
                                              unsigned short* __restrict__ Cbf,
                                              float* __restrict__ stats) {
  int bid = blockIdx.x;
  int bm_i = (bid & 7) + 8 * (bid >> 5);
  int bn_i = (bid >> 3) & 3;
  if (bm_i >= 157) return;
  const int bm = bm_i * 128, bn = bn_i * 64;
  __shared__ unsigned short As[2][128 * 64];
  __shared__ unsigned short Bs[2][64 * 64];
  const int tid = threadIdx.x, lane = tid & 63, w = tid >> 6;
  const int wr = w >> 1, wc = w & 1;
  const int srow = lane >> 3;
  const int schunk = lane & 7;
  const unsigned char* gA[4];
  const unsigned char* gB[2];
#pragma unroll
  for (int c = 0; c < 4; ++c) {
    int lr = 32 * c + w * 8 + srow;
    int r = bm + lr;
    if (r >= NODES) r = NODES - 1;
    gA[c] = (const unsigned char*)A + (size_t)r * AS * 2 + ((schunk ^ (lr & 7)) * 16);
  }
#pragma unroll
  for (int c = 0; c < 2; ++c) {
    int lr = 32 * c + w * 8 + srow;
    gB[c] = (const unsigned char*)Bt + (size_t)(bn + lr) * K * 2 + ((schunk ^ (lr & 7)) * 16);
  }

  auto stage = [&](int b, int k0) {
#pragma unroll
    for (int c = 0; c < 4; ++c) GLDS(gA[c] + 2 * k0, (char*)As[b] + c * 4096 + w * 1024);
#pragma unroll
    for (int c = 0; c < 2; ++c) GLDS(gB[c] + 2 * k0, (char*)Bs[b] + c * 4096 + w * 1024);
  };

  f32x4 acc[4][2] = {};
  stage(0, 0);
  __syncthreads();
  int cur = 0;
  for (int k0 = 0; k0 < K; k0 += 64) {
    if (k0 + 64 < K) stage(cur ^ 1, k0 + 64);
    const unsigned short* Ab = As[cur];
    const unsigned short* Bb = Bs[cur];
#pragma unroll
    for (int ks = 0; ks < 2; ++ks) {
      const int ci = ks * 4 + (lane >> 4);
      bf16x8 bfr[2];
#pragma unroll
      for (int n = 0; n < 2; ++n) {
        int rb = wc * 32 + n * 16 + (lane & 15);
        bfr[n] = *(const bf16x8*)((const char*)Bb + rb * 128 + ((ci ^ (rb & 7)) * 16));
      }
#pragma unroll
      for (int m = 0; m < 4; ++m) {
        int ra = wr * 64 + m * 16 + (lane & 15);
        bf16x8 afr = *(const bf16x8*)((const char*)Ab + ra * 128 + ((ci ^ (ra & 7)) * 16));
        acc[m][0] =
            __builtin_amdgcn_mfma_f32_16x16x32_bf16(afr, bfr[0], acc[m][0], 0, 0, 0);
        acc[m][1] =
            __builtin_amdgcn_mfma_f32_16x16x32_bf16(afr, bfr[1], acc[m][1], 0, 0, 0);
      }
    }
    __syncthreads();
    cur ^= 1;
  }

#pragma unroll
  for (int n = 0; n < 2; ++n) {
    int col = bn + wc * 32 + n * 16 + (lane & 15);
    float bv = bias[col];
    float s = 0.f, s2 = 0.f;
#pragma unroll
    for (int m = 0; m < 4; ++m) {
#pragma unroll
      for (int q = 0; q < 4; ++q) {
        int row = bm + wr * 64 + m * 16 + ((lane >> 4) * 4) + q;
        if (row < NODES) {
          float v = acc[m][n][q] + bv;
          if (OUTMODE == 0) {
            Craw[(size_t)row * 256 + col] = v;
            s += v;
            s2 = fmaf(v, v, s2);
          } else {
            Cbf[(size_t)row * STR + col] = f2bf(v);
          }
        }
      }
    }
    if (OUTMODE == 0) {
      s += __shfl_xor(s, 16);
      s += __shfl_xor(s, 32);
      s2 += __shfl_xor(s2, 16);
      s2 += __shfl_xor(s2, 32);
      if (lane < 16) {
        atomicAdd(&stats[col], s);
        atomicAdd(&stats[256 + col], s2);
      }
    }
  }
}

// ---------------- BN apply (layer 0): raw fp32 -> bf16 xs slice ----------------
__global__ __launch_bounds__(256) void k_bnapply(const float* __restrict__ raw,
                                                 const float* __restrict__ stats,
                                                 const float* __restrict__ gamma,
                                                 const float* __restrict__ beta,
                                                 unsigned short* __restrict__ out) {
  int idx = blockIdx.x * 256 + threadIdx.x;
  if (idx >= NODES * 256) return;
  int c = idx & 255;
  int rrow = idx >> 8;
  const float inv3 = 1.f / 3.f;
  float m = stats[c] * (inv3 / NODES);
  float ex2 = stats[256 + c] * (inv3 * inv3 / NODES);
  float var = ex2 - m * m;
  float v = (raw[idx] * inv3 - m) * rsqrtf(var + 1e-5f) * gamma[c] + beta[c];
  out[(size_t)rrow * STR + c] = f2bf(fmaxf(v, 0.f));
}

// ---------------- pooling (fused layer-1 BN+relu+residual) ----------------
__global__ __launch_bounds__(256) void k_pool(const float* __restrict__ raw,
                                              const float* __restrict__ stats,
                                              const float* __restrict__ gamma,
                                              const float* __restrict__ beta,
                                              const unsigned short* __restrict__ prev,
                                              const int* __restrict__ batch,
                                              float* __restrict__ pooled,
                                              float* __restrict__ gcnt) {
  int c = threadIdx.x;
  int rows_per = (NODES + gridDim.x - 1) / gridDim.x;
  int r0 = blockIdx.x * rows_per;
  int r1 = min(NODES, r0 + rows_per);
  if (r0 >= NODES) return;
  const float inv3 = 1.f / 3.f;
  float m = stats[c] * (inv3 / NODES);
  float ex2 = stats[256 + c] * (inv3 * inv3 / NODES);
  float rs = rsqrtf(ex2 - m * m + 1e-5f) * gamma[c];
  float bt = beta[c];
  float s = 0.f;
  int curg = batch[r0];
  for (int r = r0; r < r1; ++r) {
    int g = batch[r];
    if (g != curg) {
      atomicAdd(&pooled[curg * 256 + c], s);
      s = 0.f;
      curg = g;
    }
    float v = fmaxf((raw[(size_t)r * 256 + c] * inv3 - m) * rs + bt, 0.f) +
              bf2f(prev[(size_t)r * STR + c]);
    s += v;
  }
  atomicAdd(&pooled[curg * 256 + c], s);
  if (c == 0) {
    int cn = 0;
    int cg = batch[r0];
    for (int r = r0; r < r1; ++r) {
      int g = batch[r];
      if (g != cg) {
        atomicAdd(&gcnt[cg], (float)cn);
        cn = 0;
        cg = g;
      }
      cn++;
    }
    atomicAdd(&gcnt[cg], (float)cn);
  }
}

__global__ __launch_bounds__(256) void k_final(const float* __restrict__ pooled,
                                               const float* __restrict__ gcnt,
                                               const float* __restrict__ Wout,
                                               const float* __restrict__ bout,
                                               float* __restrict__ out) {
  int g = blockIdx.x;
  int h = threadIdx.x;
  float cv = fmaxf(gcnt[g], 1.f);
  float cp = fmaxf(gcnt[NGRAPH + g], 1.f);
  float v = pooled[g * 256 + h] / cv * Wout[h] +
            pooled[NGRAPH * 256 + g * 256 + h] / cp * Wout[256 + h];
#pragma unroll
  for (int s = 32; s > 0; s >>= 1) v += __shfl_down(v, s, 64);
  __shared__ float sh[4];
  if ((h & 63) == 0) sh[h >> 6] = v;
  __syncthreads();
  if (h == 0) {
    float t = sh[0] + sh[1] + sh[2] + sh[3] + bout[0];
    out[g] = 1.f / (1.f + expf(-t));
  }
}

// ---------------- host ----------------
extern "C" void kernel_launch(void* const* d_in, const int* in_sizes, int n_in,
                              void* d_out, int out_size, void* d_ws, size_t ws_size,
                              hipStream_t stream) {
  const float* x_vuln = (const float*)d_in[0];
  const float* x_patch = (const float*)d_in[1];
  const float* W_emb = (const float*)d_in[2];
  const float* b_emb = (const float*)d_in[3];
  const float* W_l = (const float*)d_in[4];
  const float* b_l = (const float*)d_in[5];
  const float* W_r = (const float*)d_in[6];
  const float* gamma = (const float*)d_in[7];
  const float* beta = (const float*)d_in[8];
  const float* W_out = (const float*)d_in[9];
  const float* b_out = (const float*)d_in[10];
  const int* edge_index = (const int*)d_in[11];
  const int* batch_vuln = (const int*)d_in[12];
  const int* batch_patch = (const int*)d_in[13];

  char* ws = (char*)d_ws;
  size_t off = 0;
  auto alloc = [&](size_t bytes) -> void* {
    void* p = ws + off;
    off = (off + bytes + 255) & ~(size_t)255;
    return p;
  };
  int* csr = (int*)alloc((size_t)NREL * EDGES * 4);
  int* rowoff = (int*)alloc((size_t)NREL * (NODES + 1) * 4);
  unsigned short* Acat[2];
  Acat[0] = (unsigned short*)alloc((size_t)NODES * STR * 2);
  Acat[1] = (unsigned short*)alloc((size_t)NODES * STR * 2);
  float* raw[2];
  raw[0] = (float*)alloc((size_t)NODES * 256 * 4);
  raw[1] = (float*)alloc((size_t)NODES * 256 * 4);
  unsigned short* xbf = (unsigned short*)alloc((size_t)2 * NODES * DIN * 2);
  unsigned short* Wt = (unsigned short*)alloc((size_t)4 * 256 * 1024 * 2);
  unsigned short* Wet = (unsigned short*)alloc((size_t)2 * 256 * DIN * 2);
  float* bsum = (float*)alloc(1024 * 4);  // [layer][dt][256]
  // ---- contiguous zero region ----
  size_t zoff0 = off;
  int* cnt = (int*)alloc((size_t)NREL * NODES * 4);
  int* cur = (int*)alloc((size_t)NREL * NODES * 4);
  float* stats = (float*)alloc((size_t)2 * 2 * 512 * 4);  // [layer][dt][{sum,sumsq}x256]
  float* pooled = (float*)alloc((size_t)2 * NGRAPH * 256 * 4);
  float* gcnt = (float*)alloc((size_t)2 * NGRAPH * 4);
  size_t zbytes = off - zoff0;
  hipMemsetAsync(ws + zoff0, 0, zbytes, stream);

  int tot_e = NREL * EDGES;
  k_hist<<<(tot_e + 255) / 256, 256, 0, stream>>>(edge_index, cnt);
  k_scan<<<NREL, 1024, 0, stream>>>(cnt, rowoff);
  k_scatter<<<(tot_e + 255) / 256, 256, 0, stream>>>(edge_index, rowoff, cur, csr);

  k_xcvt<<<(2 * NODES * DIN / 4 + 255) / 256, 256, 0, stream>>>(x_vuln, x_patch, xbf);
  k_wtrans<<<dim3(64, 16, 4), dim3(16, 16), 0, stream>>>(W_l, W_r, Wt);
  k_wembt<<<dim3(8, 16, 2), dim3(16, 16), 0, stream>>>(W_emb, Wet);
  k_bsum<<<4, 256, 0, stream>>>(b_l, bsum);

  for (int t = 0; t < 2; ++t)
    k_mfma<DIN, DIN, 1><<<640, 256, 0, stream>>>(xbf + (size_t)t * NODES * DIN,
                                                 Wet + (size_t)t * 256 * DIN,
                                                 b_emb + t * 256, nullptr,
                                                 Acat[t] + 768, nullptr);

  for (int layer = 0; layer < 2; ++layer) {
    k_agg<<<dim3(8, 157, 3), 256, 0, stream>>>(Acat[0], Acat[1], rowoff, csr);
    for (int dt = 0; dt < 2; ++dt)
      k_mfma<1024, STR, 0><<<640, 256, 0, stream>>>(
          Acat[dt], Wt + (size_t)(layer * 2 + dt) * 256 * 1024,
          bsum + (layer * 2 + dt) * 256, raw[dt], nullptr,
          stats + (layer * 2 + dt) * 512);
    if (layer == 0) {
      for (int dt = 0; dt < 2; ++dt)
        k_bnapply<<<(NODES * 256 + 255) / 256, 256, 0, stream>>>(
            raw[dt], stats + dt * 512, gamma + dt * 256, beta + dt * 256,
            Acat[dt] + 768);
    }
  }

  k_pool<<<128, 256, 0, stream>>>(raw[0], stats + 2 * 512, gamma + 2 * 256,
                                  beta + 2 * 256, Acat[0] + 768, batch_vuln, pooled,
                                  gcnt);
  k_pool<<<128, 256, 0, stream>>>(raw[1], stats + 3 * 512, gamma + 3 * 256,
                                  beta + 3 * 256, Acat[1] + 768, batch_patch,
                                  pooled + NGRAPH * 256, gcnt + NGRAPH);
  k_final<<<NGRAPH, 256, 0, stream>>>(pooled, gcnt, W_out, b_out, (float*)d_out);
}